// Round 1
// baseline (1283.187 us; speedup 1.0000x reference)
//
#include <hip/hip_runtime.h>

// ---------------------------------------------------------------------------
// HierarchicalCodebookGrounding — fp32 baseline (bf16 storage for K and S)
// B=16, N=4096, D=256, codes: cat 16 | type 128 | var 512 | spatial 16 = 672
// Pipeline:
//   kproj   : Kbf = bf16(X @ k_w^T + k_b)                     (65536x256)
//   qproj   : Qf  = codes @ W_l^T + b_l                       (672x256)
//   scores  : S = bf16(exp(clip(mask(Q K^T / 16))))  + row-sums l (atomics)
//   hmat    : H = S @ X  (fp32 acc)
//   hfinal  : H /= l ; wraw = ||H|| / tau
//   pospool : pos_acc, cnt (masked mean of positions)
//   combine : softmax/sparsify cascade -> z_cat/type/var/sp   (per batch)
//   gate    : gelu-gate, level combine, out proj, layernorm -> d_out (16x256)
// ---------------------------------------------------------------------------

#define DEV static __device__ __forceinline__

DEV float bf2f(unsigned short u) {
  return __uint_as_float(((unsigned int)u) << 16);
}
DEV unsigned short f2bf(float f) {
  unsigned int x = __float_as_uint(f);
  unsigned int r = (x + 0x7fffu + ((x >> 16) & 1u)) >> 16;
  return (unsigned short)r;
}

// ---------------------------------------------------------------------------
// kproj: Y[m][c] = sum_k X[m][k] * W[c][k] + bias[c]; store bf16.
// 64x64 tiles, BK=16, 256 threads, 4x4 micro-tile. k-major LDS tiles.
// grid (1024, 4)
// ---------------------------------------------------------------------------
__global__ __launch_bounds__(256) void kproj_kern(
    const float* __restrict__ X, const float* __restrict__ W,
    const float* __restrict__ bias, unsigned short* __restrict__ Kbf) {
  __shared__ __align__(16) float As[16][68];
  __shared__ __align__(16) float Bs[16][68];
  const int m0 = blockIdx.x * 64;
  const int c0 = blockIdx.y * 64;
  const int tid = threadIdx.x;
  const int tx = tid & 15, ty = tid >> 4;
  const int lr = tid >> 2;         // 0..63
  const int lk = (tid & 3) * 4;    // 0,4,8,12
  float acc[4][4] = {};
  for (int k0 = 0; k0 < 256; k0 += 16) {
    const float4 av = *(const float4*)&X[(size_t)(m0 + lr) * 256 + k0 + lk];
    const float4 bv = *(const float4*)&W[(size_t)(c0 + lr) * 256 + k0 + lk];
    __syncthreads();
    As[lk + 0][lr] = av.x; As[lk + 1][lr] = av.y;
    As[lk + 2][lr] = av.z; As[lk + 3][lr] = av.w;
    Bs[lk + 0][lr] = bv.x; Bs[lk + 1][lr] = bv.y;
    Bs[lk + 2][lr] = bv.z; Bs[lk + 3][lr] = bv.w;
    __syncthreads();
#pragma unroll
    for (int k = 0; k < 16; ++k) {
      const float4 a4 = *(const float4*)&As[k][ty * 4];
      const float4 b4 = *(const float4*)&Bs[k][tx * 4];
      const float a[4] = {a4.x, a4.y, a4.z, a4.w};
      const float b[4] = {b4.x, b4.y, b4.z, b4.w};
#pragma unroll
      for (int i = 0; i < 4; ++i)
#pragma unroll
        for (int j = 0; j < 4; ++j) acc[i][j] = fmaf(a[i], b[j], acc[i][j]);
    }
  }
  float bv[4];
#pragma unroll
  for (int j = 0; j < 4; ++j) bv[j] = bias[c0 + tx * 4 + j];
#pragma unroll
  for (int i = 0; i < 4; ++i) {
    const int m = m0 + ty * 4 + i;
    ushort4 sv;
    sv.x = f2bf(acc[i][0] + bv[0]);
    sv.y = f2bf(acc[i][1] + bv[1]);
    sv.z = f2bf(acc[i][2] + bv[2]);
    sv.w = f2bf(acc[i][3] + bv[3]);
    *(ushort4*)&Kbf[(size_t)m * 256 + c0 + tx * 4] = sv;
  }
}

// ---------------------------------------------------------------------------
// qproj: Q[m][j] = sum_k W_l[j][k] * code_l[m][k] + b_l[j]. grid 672.
// ---------------------------------------------------------------------------
__global__ __launch_bounds__(256) void qproj_kern(
    const float* __restrict__ cat_codes, const float* __restrict__ type_codes,
    const float* __restrict__ var_codes, const float* __restrict__ sp_codes,
    const float* __restrict__ cat_w, const float* __restrict__ cat_b,
    const float* __restrict__ type_w, const float* __restrict__ type_b,
    const float* __restrict__ var_w, const float* __restrict__ var_b,
    const float* __restrict__ sp_w, const float* __restrict__ sp_b,
    float* __restrict__ Qf) {
  const int m = blockIdx.x;
  const float* code;
  const float* W;
  const float* bias;
  if (m < 16)       { code = cat_codes  + m * 256;        W = cat_w;  bias = cat_b; }
  else if (m < 144) { code = type_codes + (m - 16) * 256; W = type_w; bias = type_b; }
  else if (m < 656) { code = var_codes  + (m - 144) * 256; W = var_w; bias = var_b; }
  else              { code = sp_codes   + (m - 656) * 256; W = sp_w;  bias = sp_b; }
  __shared__ float xs[256];
  const int t = threadIdx.x;
  xs[t] = code[t];
  __syncthreads();
  float a = bias[t];
  const float* wr = W + (size_t)t * 256;
  for (int k = 0; k < 256; k += 4) {
    const float4 w = *(const float4*)&wr[k];
    a = fmaf(w.x, xs[k], a);
    a = fmaf(w.y, xs[k + 1], a);
    a = fmaf(w.z, xs[k + 2], a);
    a = fmaf(w.w, xs[k + 3], a);
  }
  Qf[(size_t)m * 256 + t] = a;
}

// ---------------------------------------------------------------------------
// scores: per chunk of 8 batches. 64x64 tiles over (m, n), K-dim = 256.
// S[lb][m][n] = exp(clip(mask(acc/16))); l[b][m] += row sums.
// grid (11, 64, 8)
// ---------------------------------------------------------------------------
__global__ __launch_bounds__(256) void scores_kern(
    const float* __restrict__ Qf, const unsigned short* __restrict__ Kbf,
    const unsigned char* __restrict__ mask, unsigned short* __restrict__ S,
    float* __restrict__ lsum, int bbase) {
  __shared__ __align__(16) float As[16][68];
  __shared__ __align__(16) float Bs[16][68];
  __shared__ float pm[64][17];
  const int m0 = blockIdx.x * 64;
  const int n0 = blockIdx.y * 64;
  const int lb = blockIdx.z;
  const int b = bbase + lb;
  const int tid = threadIdx.x;
  const int tx = tid & 15, ty = tid >> 4;
  const int lr = tid >> 2;
  const int lk = (tid & 3) * 4;
  const unsigned short* Kb = Kbf + (size_t)b * 4096 * 256;
  float acc[4][4] = {};
  for (int k0 = 0; k0 < 256; k0 += 16) {
    const int am = m0 + lr;
    float4 av = make_float4(0.f, 0.f, 0.f, 0.f);
    if (am < 672) av = *(const float4*)&Qf[(size_t)am * 256 + k0 + lk];
    const ushort4 kv = *(const ushort4*)&Kb[(size_t)(n0 + lr) * 256 + k0 + lk];
    __syncthreads();
    As[lk + 0][lr] = av.x; As[lk + 1][lr] = av.y;
    As[lk + 2][lr] = av.z; As[lk + 3][lr] = av.w;
    Bs[lk + 0][lr] = bf2f(kv.x); Bs[lk + 1][lr] = bf2f(kv.y);
    Bs[lk + 2][lr] = bf2f(kv.z); Bs[lk + 3][lr] = bf2f(kv.w);
    __syncthreads();
#pragma unroll
    for (int k = 0; k < 16; ++k) {
      const float4 a4 = *(const float4*)&As[k][ty * 4];
      const float4 b4 = *(const float4*)&Bs[k][tx * 4];
      const float a[4] = {a4.x, a4.y, a4.z, a4.w};
      const float b[4] = {b4.x, b4.y, b4.z, b4.w};
#pragma unroll
      for (int i = 0; i < 4; ++i)
#pragma unroll
        for (int j = 0; j < 4; ++j) acc[i][j] = fmaf(a[i], b[j], acc[i][j]);
    }
  }
  const uchar4 mk4 = *(const uchar4*)&mask[(size_t)b * 4096 + n0 + tx * 4];
  const unsigned char mks[4] = {mk4.x, mk4.y, mk4.z, mk4.w};
  const float scale = 1.f / 16.f;
#pragma unroll
  for (int i = 0; i < 4; ++i) {
    const int m = m0 + ty * 4 + i;
    float p[4];
    float rs = 0.f;
#pragma unroll
    for (int j = 0; j < 4; ++j) {
      float s = acc[i][j] * scale;
      s = fminf(fmaxf(s, -50.f), 50.f);
      if (!mks[j]) s = -50.f;
      p[j] = __expf(s);
      rs += p[j];
    }
    if (m < 672) {
      ushort4 sv;
      sv.x = f2bf(p[0]); sv.y = f2bf(p[1]); sv.z = f2bf(p[2]); sv.w = f2bf(p[3]);
      *(ushort4*)&S[((size_t)lb * 672 + m) * 4096 + n0 + tx * 4] = sv;
    }
    pm[ty * 4 + i][tx] = rs;
  }
  __syncthreads();
  if (tid < 64) {
    float s = 0.f;
#pragma unroll
    for (int j = 0; j < 16; ++j) s += pm[tid][j];
    const int m = m0 + tid;
    if (m < 672) atomicAdd(&lsum[b * 672 + m], s);
  }
}

// ---------------------------------------------------------------------------
// hmat: H[b][m][d] = sum_n S[lb][m][n] * X[b][n][d]. 32x64 tiles, BK=32.
// grid (22, 4, 8)
// ---------------------------------------------------------------------------
__global__ __launch_bounds__(256) void hmat_kern(
    const unsigned short* __restrict__ S, const float* __restrict__ X,
    float* __restrict__ H, int bbase) {
  __shared__ __align__(16) float As[32][36];
  __shared__ __align__(16) float Bs[32][68];
  const int m0 = blockIdx.x * 32;
  const int d0 = blockIdx.y * 64;
  const int lb = blockIdx.z;
  const int b = bbase + lb;
  const int tid = threadIdx.x;
  const int tx = tid & 15, ty = tid >> 4;
  const int ar = tid >> 3;          // 0..31
  const int ak = (tid & 7) * 4;     // 0..28
  const int bn = tid >> 3;          // 0..31
  const int bd = (tid & 7) * 8;     // 0..56
  const float* Xb = X + (size_t)b * 4096 * 256;
  const unsigned short* Sb = S + (size_t)lb * 672 * 4096;
  float acc[2][4] = {};
  for (int n0 = 0; n0 < 4096; n0 += 32) {
    const int am = m0 + ar;
    ushort4 sv = make_ushort4(0, 0, 0, 0);
    if (am < 672) sv = *(const ushort4*)&Sb[(size_t)am * 4096 + n0 + ak];
    const float4 x0 = *(const float4*)&Xb[(size_t)(n0 + bn) * 256 + d0 + bd];
    const float4 x1 = *(const float4*)&Xb[(size_t)(n0 + bn) * 256 + d0 + bd + 4];
    __syncthreads();
    As[ak + 0][ar] = bf2f(sv.x); As[ak + 1][ar] = bf2f(sv.y);
    As[ak + 2][ar] = bf2f(sv.z); As[ak + 3][ar] = bf2f(sv.w);
    *(float4*)&Bs[bn][bd] = x0;
    *(float4*)&Bs[bn][bd + 4] = x1;
    __syncthreads();
#pragma unroll
    for (int k = 0; k < 32; ++k) {
      const float2 a2 = *(const float2*)&As[k][ty * 2];
      const float4 b4 = *(const float4*)&Bs[k][tx * 4];
      acc[0][0] = fmaf(a2.x, b4.x, acc[0][0]);
      acc[0][1] = fmaf(a2.x, b4.y, acc[0][1]);
      acc[0][2] = fmaf(a2.x, b4.z, acc[0][2]);
      acc[0][3] = fmaf(a2.x, b4.w, acc[0][3]);
      acc[1][0] = fmaf(a2.y, b4.x, acc[1][0]);
      acc[1][1] = fmaf(a2.y, b4.y, acc[1][1]);
      acc[1][2] = fmaf(a2.y, b4.z, acc[1][2]);
      acc[1][3] = fmaf(a2.y, b4.w, acc[1][3]);
    }
  }
#pragma unroll
  for (int i = 0; i < 2; ++i) {
    const int m = m0 + ty * 2 + i;
    if (m < 672) {
      const float4 v = make_float4(acc[i][0], acc[i][1], acc[i][2], acc[i][3]);
      *(float4*)&H[((size_t)b * 672 + m) * 256 + d0 + tx * 4] = v;
    }
  }
}

// ---------------------------------------------------------------------------
// hfinal: H /= l; wraw = ||H|| / tau. grid 16*672, block 256.
// ---------------------------------------------------------------------------
__global__ __launch_bounds__(256) void hfinal_kern(
    float* __restrict__ H, const float* __restrict__ lsum,
    const float* __restrict__ log_tau, float* __restrict__ wraw) {
  const int bm = blockIdx.x;
  const int t = threadIdx.x;
  __shared__ float red[256];
  const float v = H[(size_t)bm * 256 + t] / lsum[bm];
  H[(size_t)bm * 256 + t] = v;
  red[t] = v * v;
  __syncthreads();
  for (int s = 128; s > 0; s >>= 1) {
    if (t < s) red[t] += red[t + s];
    __syncthreads();
  }
  if (t == 0) {
    const float tau = fminf(fmaxf(expf(log_tau[0]) + 0.1f, 0.1f), 2.0f);
    wraw[bm] = sqrtf(red[0]) / tau;
  }
}

// ---------------------------------------------------------------------------
// pospool: pos_acc[b][d] += sum_n mask*positions; cnt[b] += sum mask.
// grid (16, 32), block 256.
// ---------------------------------------------------------------------------
__global__ __launch_bounds__(256) void pospool_kern(
    const float* __restrict__ pos, const unsigned char* __restrict__ mask,
    float* __restrict__ pacc, float* __restrict__ cnt) {
  const int b = blockIdx.x, seg = blockIdx.y, t = threadIdx.x;
  const int dg = t & 63;   // d = dg*4
  const int nl = t >> 6;   // 0..3
  const int n0 = seg * 128;
  float4 acc = make_float4(0.f, 0.f, 0.f, 0.f);
  float c = 0.f;
  const float* pb = pos + (size_t)b * 4096 * 256;
  for (int j = 0; j < 32; ++j) {
    const int n = n0 + j * 4 + nl;
    const unsigned char mk = mask[(size_t)b * 4096 + n];
    if (mk) {
      const float4 v = *(const float4*)&pb[(size_t)n * 256 + dg * 4];
      acc.x += v.x; acc.y += v.y; acc.z += v.z; acc.w += v.w;
      if (dg == 0) c += 1.f;
    }
  }
  float* pa = pacc + b * 256 + dg * 4;
  atomicAdd(pa + 0, acc.x);
  atomicAdd(pa + 1, acc.y);
  atomicAdd(pa + 2, acc.z);
  atomicAdd(pa + 3, acc.w);
  if (dg == 0) atomicAdd(&cnt[b], c);
}

// ---------------------------------------------------------------------------
// combine: softmax/sparsify cascade (serial in thread 0, tiny), then
// z_l[d] = sum_m wsp[m] * H[b][m][d].  grid 16, block 256.
// ---------------------------------------------------------------------------
__global__ __launch_bounds__(256) void combine_kern(
    const float* __restrict__ wraw, const float* __restrict__ H,
    float* __restrict__ zbuf) {
  const int b = blockIdx.x, t = threadIdx.x;
  __shared__ float wr[672];
  __shared__ float wsp[672];
  __shared__ float tmp[512];
  for (int i = t; i < 672; i += 256) wr[i] = wraw[b * 672 + i];
  __syncthreads();
  if (t == 0) {
    // --- category: wr[0..16), thr 0.1 ---
    {
      float mx = -1e30f;
      for (int i = 0; i < 16; ++i) mx = fmaxf(mx, wr[i]);
      float s = 0.f;
      for (int i = 0; i < 16; ++i) { tmp[i] = expf(wr[i] - mx); s += tmp[i]; }
      const float inv = 1.f / s;
      float s2 = 0.f;
      for (int i = 0; i < 16; ++i) {
        float w = tmp[i] * inv;
        w = (w > 0.1f) ? w : 0.f;
        tmp[i] = w; s2 += w;
      }
      const float inv2 = 1.f / (s2 + 1e-8f);
      for (int i = 0; i < 16; ++i) wsp[i] = tmp[i] * inv2;
    }
    // --- type: logits = wr[16+i]*wsp_cat[i>>3], 128, thr 0.05 ---
    {
      float mx = -1e30f;
      for (int i = 0; i < 128; ++i) {
        const float L = wr[16 + i] * wsp[i >> 3];
        tmp[i] = L; mx = fmaxf(mx, L);
      }
      float s = 0.f;
      for (int i = 0; i < 128; ++i) { tmp[i] = expf(tmp[i] - mx); s += tmp[i]; }
      const float inv = 1.f / s;
      float s2 = 0.f;
      for (int i = 0; i < 128; ++i) {
        float w = tmp[i] * inv;
        w = (w > 0.05f) ? w : 0.f;
        tmp[i] = w; s2 += w;
      }
      const float inv2 = 1.f / (s2 + 1e-8f);
      for (int i = 0; i < 128; ++i) wsp[16 + i] = tmp[i] * inv2;
    }
    // --- variant: logits = wr[144+i]*wsp_type[i>>2], 512, thr 0.025 ---
    {
      float mx = -1e30f;
      for (int i = 0; i < 512; ++i) {
        const float L = wr[144 + i] * wsp[16 + (i >> 2)];
        tmp[i] = L; mx = fmaxf(mx, L);
      }
      float s = 0.f;
      for (int i = 0; i < 512; ++i) { tmp[i] = expf(tmp[i] - mx); s += tmp[i]; }
      const float inv = 1.f / s;
      float s2 = 0.f;
      for (int i = 0; i < 512; ++i) {
        float w = tmp[i] * inv;
        w = (w > 0.025f) ? w : 0.f;
        tmp[i] = w; s2 += w;
      }
      const float inv2 = 1.f / (s2 + 1e-8f);
      for (int i = 0; i < 512; ++i) wsp[144 + i] = tmp[i] * inv2;
    }
    // --- spatial: wr[656..672), thr 0.1 ---
    {
      float mx = -1e30f;
      for (int i = 0; i < 16; ++i) mx = fmaxf(mx, wr[656 + i]);
      float s = 0.f;
      for (int i = 0; i < 16; ++i) { tmp[i] = expf(wr[656 + i] - mx); s += tmp[i]; }
      const float inv = 1.f / s;
      float s2 = 0.f;
      for (int i = 0; i < 16; ++i) {
        float w = tmp[i] * inv;
        w = (w > 0.1f) ? w : 0.f;
        tmp[i] = w; s2 += w;
      }
      const float inv2 = 1.f / (s2 + 1e-8f);
      for (int i = 0; i < 16; ++i) wsp[656 + i] = tmp[i] * inv2;
    }
  }
  __syncthreads();
  const float* Hb = H + (size_t)b * 672 * 256 + t;
  float z0 = 0.f, z1 = 0.f, z2 = 0.f, z3 = 0.f;
  for (int m = 0; m < 16; ++m)  z0 = fmaf(wsp[m],       Hb[(size_t)m * 256], z0);
  for (int m = 0; m < 128; ++m) z1 = fmaf(wsp[16 + m],  Hb[(size_t)(16 + m) * 256], z1);
  for (int m = 0; m < 512; ++m) z2 = fmaf(wsp[144 + m], Hb[(size_t)(144 + m) * 256], z2);
  for (int m = 0; m < 16; ++m)  z3 = fmaf(wsp[656 + m], Hb[(size_t)(656 + m) * 256], z3);
  zbuf[(b * 4 + 0) * 256 + t] = z0;
  zbuf[(b * 4 + 1) * 256 + t] = z1;
  zbuf[(b * 4 + 2) * 256 + t] = z2;
  zbuf[(b * 4 + 3) * 256 + t] = z3;
}

// ---------------------------------------------------------------------------
// gate: pos-gate MLP, level combine, out proj, layernorm. grid 16, block 256.
// ---------------------------------------------------------------------------
__global__ __launch_bounds__(256) void gate_kern(
    const float* __restrict__ zbuf, const float* __restrict__ pacc,
    const float* __restrict__ cnt, const float* __restrict__ g1_w,
    const float* __restrict__ g1_b, const float* __restrict__ g2_w,
    const float* __restrict__ g2_b, const float* __restrict__ out_w,
    const float* __restrict__ out_b, const float* __restrict__ ln_g,
    const float* __restrict__ ln_b, const float* __restrict__ lvlw,
    float* __restrict__ out) {
  const int b = blockIdx.x, t = threadIdx.x;
  __shared__ float gin[512];
  __shared__ float hb[256];
  __shared__ float zc[256];
  __shared__ float red[256];
  const float z0 = zbuf[(b * 4 + 0) * 256 + t];
  gin[t] = z0;
  const float c = fmaxf(cnt[b], 1.0f);
  gin[256 + t] = pacc[b * 256 + t] / c;
  __syncthreads();
  float a = g1_b[t];
  const float* w1 = g1_w + (size_t)t * 512;
  for (int k = 0; k < 512; k += 4) {
    const float4 w = *(const float4*)&w1[k];
    a = fmaf(w.x, gin[k], a);
    a = fmaf(w.y, gin[k + 1], a);
    a = fmaf(w.z, gin[k + 2], a);
    a = fmaf(w.w, gin[k + 3], a);
  }
  const float hg = 0.5f * a * (1.0f + erff(a * 0.7071067811865475f));
  hb[t] = hg;
  __syncthreads();
  float a2 = g2_b[t];
  const float* w2 = g2_w + (size_t)t * 256;
  for (int k = 0; k < 256; k += 4) {
    const float4 w = *(const float4*)&w2[k];
    a2 = fmaf(w.x, hb[k], a2);
    a2 = fmaf(w.y, hb[k + 1], a2);
    a2 = fmaf(w.z, hb[k + 2], a2);
    a2 = fmaf(w.w, hb[k + 3], a2);
  }
  const float pg = 1.0f / (1.0f + expf(-a2));
  const float l0 = lvlw[0], l1 = lvlw[1], l2 = lvlw[2], l3 = lvlw[3];
  const float mx = fmaxf(fmaxf(l0, l1), fmaxf(l2, l3));
  const float e0 = expf(l0 - mx), e1 = expf(l1 - mx);
  const float e2 = expf(l2 - mx), e3 = expf(l3 - mx);
  const float einv = 1.0f / (e0 + e1 + e2 + e3);
  const float zmix = (e0 * z0 * pg + e1 * zbuf[(b * 4 + 1) * 256 + t] +
                      e2 * zbuf[(b * 4 + 2) * 256 + t] +
                      e3 * zbuf[(b * 4 + 3) * 256 + t]) * einv;
  zc[t] = zmix;
  __syncthreads();
  float o = out_b[t];
  const float* wo = out_w + (size_t)t * 256;
  for (int k = 0; k < 256; k += 4) {
    const float4 w = *(const float4*)&wo[k];
    o = fmaf(w.x, zc[k], o);
    o = fmaf(w.y, zc[k + 1], o);
    o = fmaf(w.z, zc[k + 2], o);
    o = fmaf(w.w, zc[k + 3], o);
  }
  red[t] = o;
  __syncthreads();
  for (int s = 128; s > 0; s >>= 1) {
    if (t < s) red[t] += red[t + s];
    __syncthreads();
  }
  const float mu = red[0] / 256.f;
  __syncthreads();
  red[t] = o * o;
  __syncthreads();
  for (int s = 128; s > 0; s >>= 1) {
    if (t < s) red[t] += red[t + s];
    __syncthreads();
  }
  const float var = red[0] / 256.f - mu * mu;
  out[b * 256 + t] = (o - mu) * rsqrtf(var + 1e-5f) * ln_g[t] + ln_b[t];
}

// ---------------------------------------------------------------------------
// launch
// ---------------------------------------------------------------------------
extern "C" void kernel_launch(void* const* d_in, const int* in_sizes, int n_in,
                              void* d_out, int out_size, void* d_ws,
                              size_t ws_size, hipStream_t stream) {
  (void)in_sizes; (void)n_in; (void)out_size; (void)ws_size;
  const float* X          = (const float*)d_in[0];
  const float* positions  = (const float*)d_in[1];
  const float* cat_codes  = (const float*)d_in[2];
  const float* type_codes = (const float*)d_in[3];
  const float* var_codes  = (const float*)d_in[4];
  const float* sp_codes   = (const float*)d_in[5];
  const float* log_tau    = (const float*)d_in[6];
  const float* cat_w      = (const float*)d_in[7];
  const float* cat_b      = (const float*)d_in[8];
  const float* type_w     = (const float*)d_in[9];
  const float* type_b     = (const float*)d_in[10];
  const float* var_w      = (const float*)d_in[11];
  const float* var_b      = (const float*)d_in[12];
  const float* sp_w       = (const float*)d_in[13];
  const float* sp_b       = (const float*)d_in[14];
  const float* k_w        = (const float*)d_in[15];
  const float* k_b        = (const float*)d_in[16];
  const float* g1_w       = (const float*)d_in[17];
  const float* g1_b       = (const float*)d_in[18];
  const float* g2_w       = (const float*)d_in[19];
  const float* g2_b       = (const float*)d_in[20];
  const float* out_w      = (const float*)d_in[21];
  const float* out_b      = (const float*)d_in[22];
  const float* ln_g       = (const float*)d_in[23];
  const float* ln_b       = (const float*)d_in[24];
  const float* lvlw       = (const float*)d_in[25];
  const unsigned char* mask = (const unsigned char*)d_in[26];

  char* ws = (char*)d_ws;
  // workspace layout (bytes)
  constexpr size_t O_K   = 0;                         // bf16 K : 65536*256*2
  constexpr size_t O_Q   = O_K + 33554432;            // f32 Q  : 672*256*4
  constexpr size_t O_S   = O_Q + 688128;              // bf16 S : 8*672*4096*2
  constexpr size_t O_H   = O_S + 44040192;            // f32 H  : 16*672*256*4
  constexpr size_t O_L   = O_H + 11010048;            // f32 l  : 16*672*4
  constexpr size_t O_WR  = O_L + 43008;               // f32 wraw
  constexpr size_t O_PA  = O_WR + 43008;              // f32 pos_acc: 16*256*4
  constexpr size_t O_CNT = O_PA + 16384;              // f32 cnt: 16*4
  constexpr size_t O_Z   = O_CNT + 64;                // f32 zbuf: 16*4*256*4

  unsigned short* Kbf = (unsigned short*)(ws + O_K);
  float* Qf           = (float*)(ws + O_Q);
  unsigned short* S   = (unsigned short*)(ws + O_S);
  float* H            = (float*)(ws + O_H);
  float* lsum         = (float*)(ws + O_L);
  float* wraw         = (float*)(ws + O_WR);
  float* pacc         = (float*)(ws + O_PA);
  float* cnt          = (float*)(ws + O_CNT);
  float* zbuf         = (float*)(ws + O_Z);
  float* out          = (float*)d_out;

  hipMemsetAsync(lsum, 0, 16 * 672 * 4, stream);
  hipMemsetAsync(pacc, 0, 16 * 256 * 4, stream);
  hipMemsetAsync(cnt, 0, 16 * 4, stream);

  kproj_kern<<<dim3(1024, 4), 256, 0, stream>>>(X, k_w, k_b, Kbf);
  qproj_kern<<<dim3(672), 256, 0, stream>>>(
      cat_codes, type_codes, var_codes, sp_codes, cat_w, cat_b, type_w, type_b,
      var_w, var_b, sp_w, sp_b, Qf);
  pospool_kern<<<dim3(16, 32), 256, 0, stream>>>(positions, mask, pacc, cnt);

  for (int c = 0; c < 2; ++c) {
    scores_kern<<<dim3(11, 64, 8), 256, 0, stream>>>(Qf, Kbf, mask, S, lsum,
                                                     c * 8);
    hmat_kern<<<dim3(22, 4, 8), 256, 0, stream>>>(S, X, H, c * 8);
  }

  hfinal_kern<<<dim3(16 * 672), 256, 0, stream>>>(H, lsum, log_tau, wraw);
  combine_kern<<<dim3(16), 256, 0, stream>>>(wraw, H, zbuf);
  gate_kern<<<dim3(16), 256, 0, stream>>>(zbuf, pacc, cnt, g1_w, g1_b, g2_w,
                                          g2_b, out_w, out_b, ln_g, ln_b, lvlw,
                                          out);
}

// Round 2
// 545.622 us; speedup vs baseline: 2.3518x; 2.3518x over previous
//
#include <hip/hip_runtime.h>

// ---------------------------------------------------------------------------
// HierarchicalCodebookGrounding — round 2: bf16 MFMA for the three GEMMs.
// B=16, N=4096, D=256, codes: cat 16 | type 128 | var 512 | spatial 16 = 672
// Chunked by 8 batches (2 chunks). Per chunk:
//   kproj_mfma : Kbf = bf16(X @ k_w^T + k_b)          MFMA, 128x128 tiles
//   xT_kern    : XbfT[lb][d][n] = bf16(X[b][n][d])    transpose-convert
//   scores_mfma: S = bf16(exp(clip(mask(Q K^T/16)))), lsum atomics, 96x128
//   hmat_mfma  : Hp[slice] = S @ X  (A=S, B=XbfT, K-split 2)
//   hfinal2    : H = (Hp0+Hp1)/lsum ; wraw = ||H||/tau
// Then combine (softmax/sparsify cascade) and gate (MLP+LN) as before.
// Hp aliases Kbf (dead after scores within a chunk) to fit workspace.
// ---------------------------------------------------------------------------

#define DEV static __device__ __forceinline__

typedef short bf16x8 __attribute__((ext_vector_type(8)));
typedef float f32x4 __attribute__((ext_vector_type(4)));
typedef unsigned short u16x8 __attribute__((ext_vector_type(8)));

DEV float bf2f(unsigned short u) {
  return __uint_as_float(((unsigned int)u) << 16);
}
DEV unsigned short f2bf(float f) {
  unsigned int x = __float_as_uint(f);
  unsigned int r = (x + 0x7fffu + ((x >> 16) & 1u)) >> 16;
  return (unsigned short)r;
}

// async global->LDS, 16B per lane; LDS dest = wave-uniform base + lane*16
DEV void gl2lds16(const void* g, void* l) {
  __builtin_amdgcn_global_load_lds(
      (const __attribute__((address_space(1))) unsigned int*)g,
      (__attribute__((address_space(3))) unsigned int*)l, 16, 0, 0);
}

DEV bf16x8 pack8(const float4 a, const float4 b) {
  bf16x8 r;
  r[0] = (short)f2bf(a.x); r[1] = (short)f2bf(a.y);
  r[2] = (short)f2bf(a.z); r[3] = (short)f2bf(a.w);
  r[4] = (short)f2bf(b.x); r[5] = (short)f2bf(b.y);
  r[6] = (short)f2bf(b.z); r[7] = (short)f2bf(b.w);
  return r;
}

// ---------------------------------------------------------------------------
// kproj_mfma: Kbf[m][c] = bf16(X_chunk[m] @ W^T + bias). M=32768,N=256,K=256.
// 128x128 tiles, BK=64, 4 waves each 64x64. grid (256, 2).
// ---------------------------------------------------------------------------
__global__ __launch_bounds__(256) void kproj_mfma(
    const float* __restrict__ X, const float* __restrict__ W,
    const float* __restrict__ bias, unsigned short* __restrict__ Kbf,
    int bbase) {
  __shared__ __align__(16) unsigned short As[128 * 64];
  __shared__ __align__(16) unsigned short Bs[128 * 64];
  const int m0 = blockIdx.x * 128, c0 = blockIdx.y * 128;
  const int t = threadIdx.x, l = t & 63, w = t >> 6;
  const int wm = (w & 1) * 64, wn = (w >> 1) * 64;
  const f32x4 zero = {0.f, 0.f, 0.f, 0.f};
  f32x4 acc[4][4];
#pragma unroll
  for (int i = 0; i < 4; ++i)
#pragma unroll
    for (int j = 0; j < 4; ++j) acc[i][j] = zero;
  const size_t rowbase = (size_t)bbase * 4096 + m0;
  const int rr = t >> 3, cc = (t & 7) * 8;
  for (int kc = 0; kc < 256; kc += 64) {
    __syncthreads();
#pragma unroll
    for (int p = 0; p < 4; ++p) {
      const int r = p * 32 + rr;
      const float* xs = &X[(rowbase + r) * 256 + kc + cc];
      const float4 a0 = *(const float4*)&xs[0];
      const float4 a1 = *(const float4*)&xs[4];
      *(bf16x8*)&As[r * 64 + cc] = pack8(a0, a1);
      const float* wsrc = &W[(size_t)(c0 + r) * 256 + kc + cc];
      const float4 b0 = *(const float4*)&wsrc[0];
      const float4 b1 = *(const float4*)&wsrc[4];
      *(bf16x8*)&Bs[r * 64 + cc] = pack8(b0, b1);
    }
    __syncthreads();
#pragma unroll
    for (int ks = 0; ks < 2; ++ks) {
      const int koff = ks * 32 + ((l >> 4) & 3) * 8;
      bf16x8 a[4], b[4];
#pragma unroll
      for (int f = 0; f < 4; ++f)
        a[f] = *(const bf16x8*)&As[(wm + f * 16 + (l & 15)) * 64 + koff];
#pragma unroll
      for (int f = 0; f < 4; ++f)
        b[f] = *(const bf16x8*)&Bs[(wn + f * 16 + (l & 15)) * 64 + koff];
#pragma unroll
      for (int i = 0; i < 4; ++i)
#pragma unroll
        for (int j = 0; j < 4; ++j)
          acc[i][j] =
              __builtin_amdgcn_mfma_f32_16x16x32_bf16(a[i], b[j], acc[i][j],
                                                      0, 0, 0);
    }
  }
  const int q = (l >> 4) & 3;
#pragma unroll
  for (int j = 0; j < 4; ++j) {
    const int c = c0 + wn + j * 16 + (l & 15);
    const float bv = bias[c];
#pragma unroll
    for (int i = 0; i < 4; ++i) {
      const int mrow = m0 + wm + i * 16 + q * 4;
#pragma unroll
      for (int r = 0; r < 4; ++r)
        Kbf[(size_t)(mrow + r) * 256 + c] = f2bf(acc[i][j][r] + bv);
    }
  }
}

// ---------------------------------------------------------------------------
// xT_kern: XbfT[lb][d][n] = bf16(X[bbase+lb][n][d]). 64x64 tiles via LDS.
// grid (64, 4, 8).
// ---------------------------------------------------------------------------
__global__ __launch_bounds__(256) void xT_kern(const float* __restrict__ X,
                                               unsigned short* __restrict__ XT,
                                               int bbase) {
  __shared__ float Ls[64][65];
  const int tn = blockIdx.x, td = blockIdx.y, lb = blockIdx.z;
  const int t = threadIdx.x;
  const int nl = t >> 2, dp = (t & 3) * 16;
  const float* src =
      X + ((size_t)(bbase + lb) * 4096 + tn * 64 + nl) * 256 + td * 64 + dp;
#pragma unroll
  for (int v = 0; v < 4; ++v) {
    const float4 x = *(const float4*)&src[v * 4];
    Ls[nl][dp + v * 4 + 0] = x.x;
    Ls[nl][dp + v * 4 + 1] = x.y;
    Ls[nl][dp + v * 4 + 2] = x.z;
    Ls[nl][dp + v * 4 + 3] = x.w;
  }
  __syncthreads();
  const int dl = t >> 2, np = (t & 3) * 16;
  u16x8 h0, h1;
#pragma unroll
  for (int j = 0; j < 8; ++j) h0[j] = f2bf(Ls[np + j][dl]);
#pragma unroll
  for (int j = 0; j < 8; ++j) h1[j] = f2bf(Ls[np + 8 + j][dl]);
  unsigned short* dst =
      &XT[((size_t)lb * 256 + td * 64 + dl) * 4096 + tn * 64 + np];
  *(u16x8*)&dst[0] = h0;
  *(u16x8*)&dst[8] = h1;
}

// ---------------------------------------------------------------------------
// scores_mfma: S[lb][m][n] = bf16(exp(clip(mask(QK^T/16)))), lsum atomics.
// A=Qbf [672][256], B=Kbf[lb] [4096][256]. 96x128 tiles, BK=64, 4 waves 48x64.
// grid (7, 32, 8).
// ---------------------------------------------------------------------------
__global__ __launch_bounds__(256) void scores_mfma(
    const unsigned short* __restrict__ Qbf,
    const unsigned short* __restrict__ Kbf,
    const unsigned char* __restrict__ mask, unsigned short* __restrict__ S,
    float* __restrict__ lsum, int bbase) {
  __shared__ __align__(16) unsigned short As[96 * 64];
  __shared__ __align__(16) unsigned short Bs[128 * 64];
  const int m0 = blockIdx.x * 96, n0 = blockIdx.y * 128, lb = blockIdx.z;
  const int b = bbase + lb;
  const int t = threadIdx.x, l = t & 63, w = t >> 6;
  const int wm = (w & 1) * 48, wn = (w >> 1) * 64;
  const f32x4 zero = {0.f, 0.f, 0.f, 0.f};
  f32x4 acc[3][4];
#pragma unroll
  for (int i = 0; i < 3; ++i)
#pragma unroll
    for (int j = 0; j < 4; ++j) acc[i][j] = zero;
  const int lr = l >> 3, lc8 = (l & 7) * 8;
  for (int kc = 0; kc < 256; kc += 64) {
    __syncthreads();
#pragma unroll
    for (int i = 0; i < 3; ++i) {
      const int g = w * 3 + i;
      const int row = m0 + g * 8 + lr;
      gl2lds16(&Qbf[(size_t)row * 256 + kc + lc8], &As[g * 512]);
    }
#pragma unroll
    for (int i = 0; i < 4; ++i) {
      const int g = w * 4 + i;
      const int row = n0 + g * 8 + lr;
      gl2lds16(&Kbf[((size_t)lb * 4096 + row) * 256 + kc + lc8], &Bs[g * 512]);
    }
    __syncthreads();
#pragma unroll
    for (int ks = 0; ks < 2; ++ks) {
      const int koff = ks * 32 + ((l >> 4) & 3) * 8;
      bf16x8 a[3], b[4];
#pragma unroll
      for (int f = 0; f < 3; ++f)
        a[f] = *(const bf16x8*)&As[(wm + f * 16 + (l & 15)) * 64 + koff];
#pragma unroll
      for (int f = 0; f < 4; ++f)
        b[f] = *(const bf16x8*)&Bs[(wn + f * 16 + (l & 15)) * 64 + koff];
#pragma unroll
      for (int i = 0; i < 3; ++i)
#pragma unroll
        for (int j = 0; j < 4; ++j)
          acc[i][j] =
              __builtin_amdgcn_mfma_f32_16x16x32_bf16(a[i], b[j], acc[i][j],
                                                      0, 0, 0);
    }
  }
  const int q = (l >> 4) & 3;
  float rs[3][4];
#pragma unroll
  for (int i = 0; i < 3; ++i)
#pragma unroll
    for (int r = 0; r < 4; ++r) rs[i][r] = 0.f;
#pragma unroll
  for (int j = 0; j < 4; ++j) {
    const int n = n0 + wn + j * 16 + (l & 15);
    const bool mk = mask[(size_t)b * 4096 + n] != 0;
#pragma unroll
    for (int i = 0; i < 3; ++i) {
      const int mrow = m0 + wm + i * 16 + q * 4;
#pragma unroll
      for (int r = 0; r < 4; ++r) {
        float s = acc[i][j][r] * 0.0625f;
        s = fminf(fmaxf(s, -50.f), 50.f);
        if (!mk) s = -50.f;
        const float e = __expf(s);
        S[((size_t)lb * 672 + mrow + r) * 4096 + n] = f2bf(e);
        rs[i][r] += e;
      }
    }
  }
#pragma unroll
  for (int i = 0; i < 3; ++i) {
#pragma unroll
    for (int r = 0; r < 4; ++r) {
      float v = rs[i][r];
      v += __shfl_xor(v, 1, 64);
      v += __shfl_xor(v, 2, 64);
      v += __shfl_xor(v, 4, 64);
      v += __shfl_xor(v, 8, 64);
      if ((l & 15) == 0)
        atomicAdd(&lsum[b * 672 + m0 + wm + i * 16 + q * 4 + r], v);
    }
  }
}

// ---------------------------------------------------------------------------
// hmat_mfma: Hp[sl][lb][m][d] = sum_{n in slice} S[lb][m][n] * XT[lb][d][n].
// 96x128 tiles, BK=64, K-slice 2048. grid (7, 2, 16): z = sl*8 + lb.
// ---------------------------------------------------------------------------
__global__ __launch_bounds__(256) void hmat_mfma(
    const unsigned short* __restrict__ S, const unsigned short* __restrict__ XT,
    float* __restrict__ Hp) {
  __shared__ __align__(16) unsigned short As[96 * 64];
  __shared__ __align__(16) unsigned short Bs[128 * 64];
  const int m0 = blockIdx.x * 96, d0 = blockIdx.y * 128;
  const int lb = blockIdx.z & 7, sl = blockIdx.z >> 3;
  const int t = threadIdx.x, l = t & 63, w = t >> 6;
  const int wm = (w & 1) * 48, wn = (w >> 1) * 64;
  const f32x4 zero = {0.f, 0.f, 0.f, 0.f};
  f32x4 acc[3][4];
#pragma unroll
  for (int i = 0; i < 3; ++i)
#pragma unroll
    for (int j = 0; j < 4; ++j) acc[i][j] = zero;
  const int lr = l >> 3, lc8 = (l & 7) * 8;
  const int kend = sl * 2048 + 2048;
  for (int kc = sl * 2048; kc < kend; kc += 64) {
    __syncthreads();
#pragma unroll
    for (int i = 0; i < 3; ++i) {
      const int g = w * 3 + i;
      const int row = m0 + g * 8 + lr;
      gl2lds16(&S[((size_t)lb * 672 + row) * 4096 + kc + lc8], &As[g * 512]);
    }
#pragma unroll
    for (int i = 0; i < 4; ++i) {
      const int g = w * 4 + i;
      const int row = d0 + g * 8 + lr;
      gl2lds16(&XT[((size_t)lb * 256 + row) * 4096 + kc + lc8], &Bs[g * 512]);
    }
    __syncthreads();
#pragma unroll
    for (int ks = 0; ks < 2; ++ks) {
      const int koff = ks * 32 + ((l >> 4) & 3) * 8;
      bf16x8 a[3], b[4];
#pragma unroll
      for (int f = 0; f < 3; ++f)
        a[f] = *(const bf16x8*)&As[(wm + f * 16 + (l & 15)) * 64 + koff];
#pragma unroll
      for (int f = 0; f < 4; ++f)
        b[f] = *(const bf16x8*)&Bs[(wn + f * 16 + (l & 15)) * 64 + koff];
#pragma unroll
      for (int i = 0; i < 3; ++i)
#pragma unroll
        for (int j = 0; j < 4; ++j)
          acc[i][j] =
              __builtin_amdgcn_mfma_f32_16x16x32_bf16(a[i], b[j], acc[i][j],
                                                      0, 0, 0);
    }
  }
  const int q = (l >> 4) & 3;
#pragma unroll
  for (int j = 0; j < 4; ++j) {
    const int d = d0 + wn + j * 16 + (l & 15);
#pragma unroll
    for (int i = 0; i < 3; ++i) {
      const int mrow = m0 + wm + i * 16 + q * 4;
#pragma unroll
      for (int r = 0; r < 4; ++r)
        Hp[((size_t)(sl * 8 + lb) * 672 + mrow + r) * 256 + d] = acc[i][j][r];
    }
  }
}

// ---------------------------------------------------------------------------
// hfinal2: H = (Hp0+Hp1)/lsum ; wraw = ||H|| / tau. grid (8*672) per chunk.
// ---------------------------------------------------------------------------
__global__ __launch_bounds__(256) void hfinal2(
    const float* __restrict__ Hp, const float* __restrict__ lsum,
    const float* __restrict__ log_tau, float* __restrict__ H,
    float* __restrict__ wraw, int bbase) {
  const int bm = blockIdx.x;
  const int lb = bm / 672, m = bm % 672;
  const int b = bbase + lb;
  const int t = threadIdx.x;
  __shared__ float red[256];
  const float inv = 1.0f / lsum[b * 672 + m];
  const float v = (Hp[((size_t)lb * 672 + m) * 256 + t] +
                   Hp[((size_t)(8 + lb) * 672 + m) * 256 + t]) *
                  inv;
  H[((size_t)b * 672 + m) * 256 + t] = v;
  red[t] = v * v;
  __syncthreads();
  for (int s = 128; s > 0; s >>= 1) {
    if (t < s) red[t] += red[t + s];
    __syncthreads();
  }
  if (t == 0) {
    const float tau = fminf(fmaxf(expf(log_tau[0]) + 0.1f, 0.1f), 2.0f);
    wraw[b * 672 + m] = sqrtf(red[0]) / tau;
  }
}

// ---------------------------------------------------------------------------
// qproj: Qbf[m][j] = bf16(code_l[m] @ W_l^T + b_l). grid 672, block 256.
// ---------------------------------------------------------------------------
__global__ __launch_bounds__(256) void qproj_kern(
    const float* __restrict__ cat_codes, const float* __restrict__ type_codes,
    const float* __restrict__ var_codes, const float* __restrict__ sp_codes,
    const float* __restrict__ cat_w, const float* __restrict__ cat_b,
    const float* __restrict__ type_w, const float* __restrict__ type_b,
    const float* __restrict__ var_w, const float* __restrict__ var_b,
    const float* __restrict__ sp_w, const float* __restrict__ sp_b,
    unsigned short* __restrict__ Qbf) {
  const int m = blockIdx.x;
  const float* code;
  const float* W;
  const float* bias;
  if (m < 16)       { code = cat_codes  + m * 256;         W = cat_w;  bias = cat_b; }
  else if (m < 144) { code = type_codes + (m - 16) * 256;  W = type_w; bias = type_b; }
  else if (m < 656) { code = var_codes  + (m - 144) * 256; W = var_w;  bias = var_b; }
  else              { code = sp_codes   + (m - 656) * 256; W = sp_w;   bias = sp_b; }
  __shared__ float xs[256];
  const int t = threadIdx.x;
  xs[t] = code[t];
  __syncthreads();
  float a = bias[t];
  const float* wr = W + (size_t)t * 256;
  for (int k = 0; k < 256; k += 4) {
    const float4 w = *(const float4*)&wr[k];
    a = fmaf(w.x, xs[k], a);
    a = fmaf(w.y, xs[k + 1], a);
    a = fmaf(w.z, xs[k + 2], a);
    a = fmaf(w.w, xs[k + 3], a);
  }
  Qbf[(size_t)m * 256 + t] = f2bf(a);
}

// ---------------------------------------------------------------------------
// pospool: pos_acc[b][d] += masked sum of positions; cnt[b] += #mask.
// grid (16, 32), block 256. LDS-reduced before atomics.
// ---------------------------------------------------------------------------
__global__ __launch_bounds__(256) void pospool_kern(
    const float* __restrict__ pos, const unsigned char* __restrict__ mask,
    float* __restrict__ pacc, float* __restrict__ cnt) {
  const int b = blockIdx.x, seg = blockIdx.y, t = threadIdx.x;
  const int dg = t & 63;
  const int nl = t >> 6;
  const int n0 = seg * 128;
  float4 acc = make_float4(0.f, 0.f, 0.f, 0.f);
  float c = 0.f;
  const float* pb = pos + (size_t)b * 4096 * 256;
  for (int j = 0; j < 32; ++j) {
    const int n = n0 + j * 4 + nl;
    const unsigned char mk = mask[(size_t)b * 4096 + n];
    if (mk) {
      const float4 v = *(const float4*)&pb[(size_t)n * 256 + dg * 4];
      acc.x += v.x; acc.y += v.y; acc.z += v.z; acc.w += v.w;
      if (dg == 0) c += 1.f;
    }
  }
  __shared__ float4 red4[256];
  __shared__ float redc[4];
  red4[t] = acc;
  if (dg == 0) redc[nl] = c;
  __syncthreads();
  if (t < 64) {
    float4 s = red4[t];
    const float4 s1 = red4[t + 64], s2 = red4[t + 128], s3 = red4[t + 192];
    s.x += s1.x + s2.x + s3.x;
    s.y += s1.y + s2.y + s3.y;
    s.z += s1.z + s2.z + s3.z;
    s.w += s1.w + s2.w + s3.w;
    float* pa = pacc + b * 256 + t * 4;
    atomicAdd(pa + 0, s.x);
    atomicAdd(pa + 1, s.y);
    atomicAdd(pa + 2, s.z);
    atomicAdd(pa + 3, s.w);
    if (t == 0) atomicAdd(&cnt[b], redc[0] + redc[1] + redc[2] + redc[3]);
  }
}

// ---------------------------------------------------------------------------
// combine: softmax/sparsify cascade, then z_l = sum_m wsp*H. grid 16.
// ---------------------------------------------------------------------------
__global__ __launch_bounds__(256) void combine_kern(
    const float* __restrict__ wraw, const float* __restrict__ H,
    float* __restrict__ zbuf) {
  const int b = blockIdx.x, t = threadIdx.x;
  __shared__ float wr[672];
  __shared__ float wsp[672];
  __shared__ float tmp[512];
  for (int i = t; i < 672; i += 256) wr[i] = wraw[b * 672 + i];
  __syncthreads();
  if (t == 0) {
    {
      float mx = -1e30f;
      for (int i = 0; i < 16; ++i) mx = fmaxf(mx, wr[i]);
      float s = 0.f;
      for (int i = 0; i < 16; ++i) { tmp[i] = expf(wr[i] - mx); s += tmp[i]; }
      const float inv = 1.f / s;
      float s2 = 0.f;
      for (int i = 0; i < 16; ++i) {
        float w = tmp[i] * inv;
        w = (w > 0.1f) ? w : 0.f;
        tmp[i] = w; s2 += w;
      }
      const float inv2 = 1.f / (s2 + 1e-8f);
      for (int i = 0; i < 16; ++i) wsp[i] = tmp[i] * inv2;
    }
    {
      float mx = -1e30f;
      for (int i = 0; i < 128; ++i) {
        const float L = wr[16 + i] * wsp[i >> 3];
        tmp[i] = L; mx = fmaxf(mx, L);
      }
      float s = 0.f;
      for (int i = 0; i < 128; ++i) { tmp[i] = expf(tmp[i] - mx); s += tmp[i]; }
      const float inv = 1.f / s;
      float s2 = 0.f;
      for (int i = 0; i < 128; ++i) {
        float w = tmp[i] * inv;
        w = (w > 0.05f) ? w : 0.f;
        tmp[i] = w; s2 += w;
      }
      const float inv2 = 1.f / (s2 + 1e-8f);
      for (int i = 0; i < 128; ++i) wsp[16 + i] = tmp[i] * inv2;
    }
    {
      float mx = -1e30f;
      for (int i = 0; i < 512; ++i) {
        const float L = wr[144 + i] * wsp[16 + (i >> 2)];
        tmp[i] = L; mx = fmaxf(mx, L);
      }
      float s = 0.f;
      for (int i = 0; i < 512; ++i) { tmp[i] = expf(tmp[i] - mx); s += tmp[i]; }
      const float inv = 1.f / s;
      float s2 = 0.f;
      for (int i = 0; i < 512; ++i) {
        float w = tmp[i] * inv;
        w = (w > 0.025f) ? w : 0.f;
        tmp[i] = w; s2 += w;
      }
      const float inv2 = 1.f / (s2 + 1e-8f);
      for (int i = 0; i < 512; ++i) wsp[144 + i] = tmp[i] * inv2;
    }
    {
      float mx = -1e30f;
      for (int i = 0; i < 16; ++i) mx = fmaxf(mx, wr[656 + i]);
      float s = 0.f;
      for (int i = 0; i < 16; ++i) { tmp[i] = expf(wr[656 + i] - mx); s += tmp[i]; }
      const float inv = 1.f / s;
      float s2 = 0.f;
      for (int i = 0; i < 16; ++i) {
        float w = tmp[i] * inv;
        w = (w > 0.1f) ? w : 0.f;
        tmp[i] = w; s2 += w;
      }
      const float inv2 = 1.f / (s2 + 1e-8f);
      for (int i = 0; i < 16; ++i) wsp[656 + i] = tmp[i] * inv2;
    }
  }
  __syncthreads();
  const float* Hb = H + (size_t)b * 672 * 256 + t;
  float z0 = 0.f, z1 = 0.f, z2 = 0.f, z3 = 0.f;
  for (int m = 0; m < 16; ++m)  z0 = fmaf(wsp[m],       Hb[(size_t)m * 256], z0);
  for (int m = 0; m < 128; ++m) z1 = fmaf(wsp[16 + m],  Hb[(size_t)(16 + m) * 256], z1);
  for (int m = 0; m < 512; ++m) z2 = fmaf(wsp[144 + m], Hb[(size_t)(144 + m) * 256], z2);
  for (int m = 0; m < 16; ++m)  z3 = fmaf(wsp[656 + m], Hb[(size_t)(656 + m) * 256], z3);
  zbuf[(b * 4 + 0) * 256 + t] = z0;
  zbuf[(b * 4 + 1) * 256 + t] = z1;
  zbuf[(b * 4 + 2) * 256 + t] = z2;
  zbuf[(b * 4 + 3) * 256 + t] = z3;
}

// ---------------------------------------------------------------------------
// gate: pos-gate MLP, level combine, out proj, layernorm. grid 16.
// ---------------------------------------------------------------------------
__global__ __launch_bounds__(256) void gate_kern(
    const float* __restrict__ zbuf, const float* __restrict__ pacc,
    const float* __restrict__ cnt, const float* __restrict__ g1_w,
    const float* __restrict__ g1_b, const float* __restrict__ g2_w,
    const float* __restrict__ g2_b, const float* __restrict__ out_w,
    const float* __restrict__ out_b, const float* __restrict__ ln_g,
    const float* __restrict__ ln_b, const float* __restrict__ lvlw,
    float* __restrict__ out) {
  const int b = blockIdx.x, t = threadIdx.x;
  __shared__ float gin[512];
  __shared__ float hb[256];
  __shared__ float zc[256];
  __shared__ float red[256];
  const float z0 = zbuf[(b * 4 + 0) * 256 + t];
  gin[t] = z0;
  const float c = fmaxf(cnt[b], 1.0f);
  gin[256 + t] = pacc[b * 256 + t] / c;
  __syncthreads();
  float a = g1_b[t];
  const float* w1 = g1_w + (size_t)t * 512;
  for (int k = 0; k < 512; k += 4) {
    const float4 w = *(const float4*)&w1[k];
    a = fmaf(w.x, gin[k], a);
    a = fmaf(w.y, gin[k + 1], a);
    a = fmaf(w.z, gin[k + 2], a);
    a = fmaf(w.w, gin[k + 3], a);
  }
  const float hg = 0.5f * a * (1.0f + erff(a * 0.7071067811865475f));
  hb[t] = hg;
  __syncthreads();
  float a2 = g2_b[t];
  const float* w2 = g2_w + (size_t)t * 256;
  for (int k = 0; k < 256; k += 4) {
    const float4 w = *(const float4*)&w2[k];
    a2 = fmaf(w.x, hb[k], a2);
    a2 = fmaf(w.y, hb[k + 1], a2);
    a2 = fmaf(w.z, hb[k + 2], a2);
    a2 = fmaf(w.w, hb[k + 3], a2);
  }
  const float pg = 1.0f / (1.0f + expf(-a2));
  const float l0 = lvlw[0], l1 = lvlw[1], l2 = lvlw[2], l3 = lvlw[3];
  const float mx = fmaxf(fmaxf(l0, l1), fmaxf(l2, l3));
  const float e0 = expf(l0 - mx), e1 = expf(l1 - mx);
  const float e2 = expf(l2 - mx), e3 = expf(l3 - mx);
  const float einv = 1.0f / (e0 + e1 + e2 + e3);
  const float zmix = (e0 * z0 * pg + e1 * zbuf[(b * 4 + 1) * 256 + t] +
                      e2 * zbuf[(b * 4 + 2) * 256 + t] +
                      e3 * zbuf[(b * 4 + 3) * 256 + t]) * einv;
  zc[t] = zmix;
  __syncthreads();
  float o = out_b[t];
  const float* wo = out_w + (size_t)t * 256;
  for (int k = 0; k < 256; k += 4) {
    const float4 w = *(const float4*)&wo[k];
    o = fmaf(w.x, zc[k], o);
    o = fmaf(w.y, zc[k + 1], o);
    o = fmaf(w.z, zc[k + 2], o);
    o = fmaf(w.w, zc[k + 3], o);
  }
  red[t] = o;
  __syncthreads();
  for (int s = 128; s > 0; s >>= 1) {
    if (t < s) red[t] += red[t + s];
    __syncthreads();
  }
  const float mu = red[0] / 256.f;
  __syncthreads();
  red[t] = o * o;
  __syncthreads();
  for (int s = 128; s > 0; s >>= 1) {
    if (t < s) red[t] += red[t + s];
    __syncthreads();
  }
  const float var = red[0] / 256.f - mu * mu;
  out[b * 256 + t] = (o - mu) * rsqrtf(var + 1e-5f) * ln_g[t] + ln_b[t];
}

// ---------------------------------------------------------------------------
// launch
// ---------------------------------------------------------------------------
extern "C" void kernel_launch(void* const* d_in, const int* in_sizes, int n_in,
                              void* d_out, int out_size, void* d_ws,
                              size_t ws_size, hipStream_t stream) {
  (void)in_sizes; (void)n_in; (void)out_size; (void)ws_size;
  const float* X          = (const float*)d_in[0];
  const float* positions  = (const float*)d_in[1];
  const float* cat_codes  = (const float*)d_in[2];
  const float* type_codes = (const float*)d_in[3];
  const float* var_codes  = (const float*)d_in[4];
  const float* sp_codes   = (const float*)d_in[5];
  const float* log_tau    = (const float*)d_in[6];
  const float* cat_w      = (const float*)d_in[7];
  const float* cat_b      = (const float*)d_in[8];
  const float* type_w     = (const float*)d_in[9];
  const float* type_b     = (const float*)d_in[10];
  const float* var_w      = (const float*)d_in[11];
  const float* var_b      = (const float*)d_in[12];
  const float* sp_w       = (const float*)d_in[13];
  const float* sp_b       = (const float*)d_in[14];
  const float* k_w        = (const float*)d_in[15];
  const float* k_b        = (const float*)d_in[16];
  const float* g1_w       = (const float*)d_in[17];
  const float* g1_b       = (const float*)d_in[18];
  const float* g2_w       = (const float*)d_in[19];
  const float* g2_b       = (const float*)d_in[20];
  const float* out_w      = (const float*)d_in[21];
  const float* out_b      = (const float*)d_in[22];
  const float* ln_g       = (const float*)d_in[23];
  const float* ln_b       = (const float*)d_in[24];
  const float* lvlw       = (const float*)d_in[25];
  const unsigned char* mask = (const unsigned char*)d_in[26];

  char* ws = (char*)d_ws;
  // workspace layout (bytes); Hp aliases Kbf (dead after scores in a chunk)
  constexpr size_t O_KBF = 0;          // bf16 Kbf [8][4096][256] = 16777216 / f32 Hp [2][8][672][256] = 11010048
  constexpr size_t O_QBF = 16777216;   // bf16 Qbf [672][256] = 344064
  constexpr size_t O_S   = 17121280;   // bf16 S [8][672][4096] = 44040192
  constexpr size_t O_XT  = 61161472;   // bf16 XbfT [8][256][4096] = 16777216
  constexpr size_t O_H   = 77938688;   // f32 H [16][672][256] = 11010048
  constexpr size_t O_L   = 88948736;   // f32 lsum [16][672]
  constexpr size_t O_WR  = 88991744;   // f32 wraw [16][672]
  constexpr size_t O_PA  = 89034752;   // f32 pacc [16][256]
  constexpr size_t O_CNT = 89051136;   // f32 cnt [16]
  constexpr size_t O_Z   = 89051200;   // f32 zbuf [16][4][256]

  unsigned short* Kbf = (unsigned short*)(ws + O_KBF);
  float* Hp           = (float*)(ws + O_KBF);
  unsigned short* Qbf = (unsigned short*)(ws + O_QBF);
  unsigned short* S   = (unsigned short*)(ws + O_S);
  unsigned short* XT  = (unsigned short*)(ws + O_XT);
  float* H            = (float*)(ws + O_H);
  float* lsum         = (float*)(ws + O_L);
  float* wraw         = (float*)(ws + O_WR);
  float* pacc         = (float*)(ws + O_PA);
  float* cnt          = (float*)(ws + O_CNT);
  float* zbuf         = (float*)(ws + O_Z);
  float* out          = (float*)d_out;

  hipMemsetAsync(lsum, 0, 16 * 672 * 4, stream);
  hipMemsetAsync(pacc, 0, 16 * 256 * 4, stream);
  hipMemsetAsync(cnt, 0, 64, stream);

  qproj_kern<<<dim3(672), 256, 0, stream>>>(
      cat_codes, type_codes, var_codes, sp_codes, cat_w, cat_b, type_w, type_b,
      var_w, var_b, sp_w, sp_b, Qbf);
  pospool_kern<<<dim3(16, 32), 256, 0, stream>>>(positions, mask, pacc, cnt);

  for (int c = 0; c < 2; ++c) {
    const int bbase = c * 8;
    kproj_mfma<<<dim3(256, 2), 256, 0, stream>>>(X, k_w, k_b, Kbf, bbase);
    xT_kern<<<dim3(64, 4, 8), 256, 0, stream>>>(X, XT, bbase);
    scores_mfma<<<dim3(7, 32, 8), 256, 0, stream>>>(Qbf, Kbf, mask, S, lsum,
                                                    bbase);
    hmat_mfma<<<dim3(7, 2, 16), 256, 0, stream>>>(S, XT, Hp);
    hfinal2<<<dim3(8 * 672), 256, 0, stream>>>(Hp, lsum, log_tau, H, wraw,
                                               bbase);
  }

  combine_kern<<<dim3(16), 256, 0, stream>>>(wraw, H, zbuf);
  gate_kern<<<dim3(16), 256, 0, stream>>>(zbuf, pacc, cnt, g1_w, g1_b, g2_w,
                                          g2_b, out_w, out_b, ln_g, ln_b, lvlw,
                                          out);
}

// Round 3
// 518.567 us; speedup vs baseline: 2.4745x; 1.0522x over previous
//
#include <hip/hip_runtime.h>

// ---------------------------------------------------------------------------
// HierarchicalCodebookGrounding — round 3: parallel combine.
// B=16, N=4096, D=256, codes: cat 16 | type 128 | var 512 | spatial 16 = 672
// Chunked by 8 batches (2 chunks). Per chunk:
//   kproj_mfma : Kbf = bf16(X @ k_w^T + k_b)          MFMA, 128x128 tiles
//   xT_kern    : XbfT[lb][d][n] = bf16(X[b][n][d])    transpose-convert
//   scores_mfma: S = bf16(exp(clip(mask(Q K^T/16)))), lsum atomics, 96x128
//   hmat_mfma  : Hp[slice] = S @ X  (A=S, B=XbfT, K-split 2)
//   hfinal2    : H = (Hp0+Hp1)/lsum ; wraw = ||H||/tau
// combine: wave-parallel softmax/sparsify cascade (all waves duplicate,
//          __syncthreads between stages) + uniform-zero-skip z-sum.
// gate: MLP + level combine + LN.
// Hp aliases Kbf (dead after scores within a chunk) to fit workspace.
// ---------------------------------------------------------------------------

#define DEV static __device__ __forceinline__

typedef short bf16x8 __attribute__((ext_vector_type(8)));
typedef float f32x4 __attribute__((ext_vector_type(4)));
typedef unsigned short u16x8 __attribute__((ext_vector_type(8)));

DEV float bf2f(unsigned short u) {
  return __uint_as_float(((unsigned int)u) << 16);
}
DEV unsigned short f2bf(float f) {
  unsigned int x = __float_as_uint(f);
  unsigned int r = (x + 0x7fffu + ((x >> 16) & 1u)) >> 16;
  return (unsigned short)r;
}

// async global->LDS, 16B per lane; LDS dest = wave-uniform base + lane*16
DEV void gl2lds16(const void* g, void* l) {
  __builtin_amdgcn_global_load_lds(
      (const __attribute__((address_space(1))) unsigned int*)g,
      (__attribute__((address_space(3))) unsigned int*)l, 16, 0, 0);
}

DEV bf16x8 pack8(const float4 a, const float4 b) {
  bf16x8 r;
  r[0] = (short)f2bf(a.x); r[1] = (short)f2bf(a.y);
  r[2] = (short)f2bf(a.z); r[3] = (short)f2bf(a.w);
  r[4] = (short)f2bf(b.x); r[5] = (short)f2bf(b.y);
  r[6] = (short)f2bf(b.z); r[7] = (short)f2bf(b.w);
  return r;
}

DEV float wave_max(float v) {
#pragma unroll
  for (int m = 1; m < 64; m <<= 1) v = fmaxf(v, __shfl_xor(v, m, 64));
  return v;
}
DEV float wave_sum(float v) {
#pragma unroll
  for (int m = 1; m < 64; m <<= 1) v += __shfl_xor(v, m, 64);
  return v;
}

// ---------------------------------------------------------------------------
// kproj_mfma: Kbf[m][c] = bf16(X_chunk[m] @ W^T + bias). M=32768,N=256,K=256.
// 128x128 tiles, BK=64, 4 waves each 64x64. grid (256, 2).
// ---------------------------------------------------------------------------
__global__ __launch_bounds__(256) void kproj_mfma(
    const float* __restrict__ X, const float* __restrict__ W,
    const float* __restrict__ bias, unsigned short* __restrict__ Kbf,
    int bbase) {
  __shared__ __align__(16) unsigned short As[128 * 64];
  __shared__ __align__(16) unsigned short Bs[128 * 64];
  const int m0 = blockIdx.x * 128, c0 = blockIdx.y * 128;
  const int t = threadIdx.x, l = t & 63, w = t >> 6;
  const int wm = (w & 1) * 64, wn = (w >> 1) * 64;
  const f32x4 zero = {0.f, 0.f, 0.f, 0.f};
  f32x4 acc[4][4];
#pragma unroll
  for (int i = 0; i < 4; ++i)
#pragma unroll
    for (int j = 0; j < 4; ++j) acc[i][j] = zero;
  const size_t rowbase = (size_t)bbase * 4096 + m0;
  const int rr = t >> 3, cc = (t & 7) * 8;
  for (int kc = 0; kc < 256; kc += 64) {
    __syncthreads();
#pragma unroll
    for (int p = 0; p < 4; ++p) {
      const int r = p * 32 + rr;
      const float* xs = &X[(rowbase + r) * 256 + kc + cc];
      const float4 a0 = *(const float4*)&xs[0];
      const float4 a1 = *(const float4*)&xs[4];
      *(bf16x8*)&As[r * 64 + cc] = pack8(a0, a1);
      const float* wsrc = &W[(size_t)(c0 + r) * 256 + kc + cc];
      const float4 b0 = *(const float4*)&wsrc[0];
      const float4 b1 = *(const float4*)&wsrc[4];
      *(bf16x8*)&Bs[r * 64 + cc] = pack8(b0, b1);
    }
    __syncthreads();
#pragma unroll
    for (int ks = 0; ks < 2; ++ks) {
      const int koff = ks * 32 + ((l >> 4) & 3) * 8;
      bf16x8 a[4], b[4];
#pragma unroll
      for (int f = 0; f < 4; ++f)
        a[f] = *(const bf16x8*)&As[(wm + f * 16 + (l & 15)) * 64 + koff];
#pragma unroll
      for (int f = 0; f < 4; ++f)
        b[f] = *(const bf16x8*)&Bs[(wn + f * 16 + (l & 15)) * 64 + koff];
#pragma unroll
      for (int i = 0; i < 4; ++i)
#pragma unroll
        for (int j = 0; j < 4; ++j)
          acc[i][j] =
              __builtin_amdgcn_mfma_f32_16x16x32_bf16(a[i], b[j], acc[i][j],
                                                      0, 0, 0);
    }
  }
  const int q = (l >> 4) & 3;
#pragma unroll
  for (int j = 0; j < 4; ++j) {
    const int c = c0 + wn + j * 16 + (l & 15);
    const float bv = bias[c];
#pragma unroll
    for (int i = 0; i < 4; ++i) {
      const int mrow = m0 + wm + i * 16 + q * 4;
#pragma unroll
      for (int r = 0; r < 4; ++r)
        Kbf[(size_t)(mrow + r) * 256 + c] = f2bf(acc[i][j][r] + bv);
    }
  }
}

// ---------------------------------------------------------------------------
// xT_kern: XbfT[lb][d][n] = bf16(X[bbase+lb][n][d]). 64x64 tiles via LDS.
// grid (64, 4, 8).
// ---------------------------------------------------------------------------
__global__ __launch_bounds__(256) void xT_kern(const float* __restrict__ X,
                                               unsigned short* __restrict__ XT,
                                               int bbase) {
  __shared__ float Ls[64][65];
  const int tn = blockIdx.x, td = blockIdx.y, lb = blockIdx.z;
  const int t = threadIdx.x;
  const int nl = t >> 2, dp = (t & 3) * 16;
  const float* src =
      X + ((size_t)(bbase + lb) * 4096 + tn * 64 + nl) * 256 + td * 64 + dp;
#pragma unroll
  for (int v = 0; v < 4; ++v) {
    const float4 x = *(const float4*)&src[v * 4];
    Ls[nl][dp + v * 4 + 0] = x.x;
    Ls[nl][dp + v * 4 + 1] = x.y;
    Ls[nl][dp + v * 4 + 2] = x.z;
    Ls[nl][dp + v * 4 + 3] = x.w;
  }
  __syncthreads();
  const int dl = t >> 2, np = (t & 3) * 16;
  u16x8 h0, h1;
#pragma unroll
  for (int j = 0; j < 8; ++j) h0[j] = f2bf(Ls[np + j][dl]);
#pragma unroll
  for (int j = 0; j < 8; ++j) h1[j] = f2bf(Ls[np + 8 + j][dl]);
  unsigned short* dst =
      &XT[((size_t)lb * 256 + td * 64 + dl) * 4096 + tn * 64 + np];
  *(u16x8*)&dst[0] = h0;
  *(u16x8*)&dst[8] = h1;
}

// ---------------------------------------------------------------------------
// scores_mfma: S[lb][m][n] = bf16(exp(clip(mask(QK^T/16)))), lsum atomics.
// A=Qbf [672][256], B=Kbf[lb] [4096][256]. 96x128 tiles, BK=64, 4 waves 48x64.
// grid (7, 32, 8).
// ---------------------------------------------------------------------------
__global__ __launch_bounds__(256) void scores_mfma(
    const unsigned short* __restrict__ Qbf,
    const unsigned short* __restrict__ Kbf,
    const unsigned char* __restrict__ mask, unsigned short* __restrict__ S,
    float* __restrict__ lsum, int bbase) {
  __shared__ __align__(16) unsigned short As[96 * 64];
  __shared__ __align__(16) unsigned short Bs[128 * 64];
  const int m0 = blockIdx.x * 96, n0 = blockIdx.y * 128, lb = blockIdx.z;
  const int b = bbase + lb;
  const int t = threadIdx.x, l = t & 63, w = t >> 6;
  const int wm = (w & 1) * 48, wn = (w >> 1) * 64;
  const f32x4 zero = {0.f, 0.f, 0.f, 0.f};
  f32x4 acc[3][4];
#pragma unroll
  for (int i = 0; i < 3; ++i)
#pragma unroll
    for (int j = 0; j < 4; ++j) acc[i][j] = zero;
  const int lr = l >> 3, lc8 = (l & 7) * 8;
  for (int kc = 0; kc < 256; kc += 64) {
    __syncthreads();
#pragma unroll
    for (int i = 0; i < 3; ++i) {
      const int g = w * 3 + i;
      const int row = m0 + g * 8 + lr;
      gl2lds16(&Qbf[(size_t)row * 256 + kc + lc8], &As[g * 512]);
    }
#pragma unroll
    for (int i = 0; i < 4; ++i) {
      const int g = w * 4 + i;
      const int row = n0 + g * 8 + lr;
      gl2lds16(&Kbf[((size_t)lb * 4096 + row) * 256 + kc + lc8], &Bs[g * 512]);
    }
    __syncthreads();
#pragma unroll
    for (int ks = 0; ks < 2; ++ks) {
      const int koff = ks * 32 + ((l >> 4) & 3) * 8;
      bf16x8 a[3], b[4];
#pragma unroll
      for (int f = 0; f < 3; ++f)
        a[f] = *(const bf16x8*)&As[(wm + f * 16 + (l & 15)) * 64 + koff];
#pragma unroll
      for (int f = 0; f < 4; ++f)
        b[f] = *(const bf16x8*)&Bs[(wn + f * 16 + (l & 15)) * 64 + koff];
#pragma unroll
      for (int i = 0; i < 3; ++i)
#pragma unroll
        for (int j = 0; j < 4; ++j)
          acc[i][j] =
              __builtin_amdgcn_mfma_f32_16x16x32_bf16(a[i], b[j], acc[i][j],
                                                      0, 0, 0);
    }
  }
  const int q = (l >> 4) & 3;
  float rs[3][4];
#pragma unroll
  for (int i = 0; i < 3; ++i)
#pragma unroll
    for (int r = 0; r < 4; ++r) rs[i][r] = 0.f;
#pragma unroll
  for (int j = 0; j < 4; ++j) {
    const int n = n0 + wn + j * 16 + (l & 15);
    const bool mk = mask[(size_t)b * 4096 + n] != 0;
#pragma unroll
    for (int i = 0; i < 3; ++i) {
      const int mrow = m0 + wm + i * 16 + q * 4;
#pragma unroll
      for (int r = 0; r < 4; ++r) {
        float s = acc[i][j][r] * 0.0625f;
        s = fminf(fmaxf(s, -50.f), 50.f);
        if (!mk) s = -50.f;
        const float e = __expf(s);
        S[((size_t)lb * 672 + mrow + r) * 4096 + n] = f2bf(e);
        rs[i][r] += e;
      }
    }
  }
#pragma unroll
  for (int i = 0; i < 3; ++i) {
#pragma unroll
    for (int r = 0; r < 4; ++r) {
      float v = rs[i][r];
      v += __shfl_xor(v, 1, 64);
      v += __shfl_xor(v, 2, 64);
      v += __shfl_xor(v, 4, 64);
      v += __shfl_xor(v, 8, 64);
      if ((l & 15) == 0)
        atomicAdd(&lsum[b * 672 + m0 + wm + i * 16 + q * 4 + r], v);
    }
  }
}

// ---------------------------------------------------------------------------
// hmat_mfma: Hp[sl][lb][m][d] = sum_{n in slice} S[lb][m][n] * XT[lb][d][n].
// 96x128 tiles, BK=64, K-slice 2048. grid (7, 2, 16): z = sl*8 + lb.
// ---------------------------------------------------------------------------
__global__ __launch_bounds__(256) void hmat_mfma(
    const unsigned short* __restrict__ S, const unsigned short* __restrict__ XT,
    float* __restrict__ Hp) {
  __shared__ __align__(16) unsigned short As[96 * 64];
  __shared__ __align__(16) unsigned short Bs[128 * 64];
  const int m0 = blockIdx.x * 96, d0 = blockIdx.y * 128;
  const int lb = blockIdx.z & 7, sl = blockIdx.z >> 3;
  const int t = threadIdx.x, l = t & 63, w = t >> 6;
  const int wm = (w & 1) * 48, wn = (w >> 1) * 64;
  const f32x4 zero = {0.f, 0.f, 0.f, 0.f};
  f32x4 acc[3][4];
#pragma unroll
  for (int i = 0; i < 3; ++i)
#pragma unroll
    for (int j = 0; j < 4; ++j) acc[i][j] = zero;
  const int lr = l >> 3, lc8 = (l & 7) * 8;
  const int kend = sl * 2048 + 2048;
  for (int kc = sl * 2048; kc < kend; kc += 64) {
    __syncthreads();
#pragma unroll
    for (int i = 0; i < 3; ++i) {
      const int g = w * 3 + i;
      const int row = m0 + g * 8 + lr;
      gl2lds16(&S[((size_t)lb * 672 + row) * 4096 + kc + lc8], &As[g * 512]);
    }
#pragma unroll
    for (int i = 0; i < 4; ++i) {
      const int g = w * 4 + i;
      const int row = d0 + g * 8 + lr;
      gl2lds16(&XT[((size_t)lb * 256 + row) * 4096 + kc + lc8], &Bs[g * 512]);
    }
    __syncthreads();
#pragma unroll
    for (int ks = 0; ks < 2; ++ks) {
      const int koff = ks * 32 + ((l >> 4) & 3) * 8;
      bf16x8 a[3], b[4];
#pragma unroll
      for (int f = 0; f < 3; ++f)
        a[f] = *(const bf16x8*)&As[(wm + f * 16 + (l & 15)) * 64 + koff];
#pragma unroll
      for (int f = 0; f < 4; ++f)
        b[f] = *(const bf16x8*)&Bs[(wn + f * 16 + (l & 15)) * 64 + koff];
#pragma unroll
      for (int i = 0; i < 3; ++i)
#pragma unroll
        for (int j = 0; j < 4; ++j)
          acc[i][j] =
              __builtin_amdgcn_mfma_f32_16x16x32_bf16(a[i], b[j], acc[i][j],
                                                      0, 0, 0);
    }
  }
  const int q = (l >> 4) & 3;
#pragma unroll
  for (int j = 0; j < 4; ++j) {
    const int d = d0 + wn + j * 16 + (l & 15);
#pragma unroll
    for (int i = 0; i < 3; ++i) {
      const int mrow = m0 + wm + i * 16 + q * 4;
#pragma unroll
      for (int r = 0; r < 4; ++r)
        Hp[((size_t)(sl * 8 + lb) * 672 + mrow + r) * 256 + d] = acc[i][j][r];
    }
  }
}

// ---------------------------------------------------------------------------
// hfinal2: H = (Hp0+Hp1)/lsum ; wraw = ||H|| / tau. grid (8*672) per chunk.
// ---------------------------------------------------------------------------
__global__ __launch_bounds__(256) void hfinal2(
    const float* __restrict__ Hp, const float* __restrict__ lsum,
    const float* __restrict__ log_tau, float* __restrict__ H,
    float* __restrict__ wraw, int bbase) {
  const int bm = blockIdx.x;
  const int lb = bm / 672, m = bm % 672;
  const int b = bbase + lb;
  const int t = threadIdx.x;
  __shared__ float red[256];
  const float inv = 1.0f / lsum[b * 672 + m];
  const float v = (Hp[((size_t)lb * 672 + m) * 256 + t] +
                   Hp[((size_t)(8 + lb) * 672 + m) * 256 + t]) *
                  inv;
  H[((size_t)b * 672 + m) * 256 + t] = v;
  red[t] = v * v;
  __syncthreads();
  for (int s = 128; s > 0; s >>= 1) {
    if (t < s) red[t] += red[t + s];
    __syncthreads();
  }
  if (t == 0) {
    const float tau = fminf(fmaxf(expf(log_tau[0]) + 0.1f, 0.1f), 2.0f);
    wraw[b * 672 + m] = sqrtf(red[0]) / tau;
  }
}

// ---------------------------------------------------------------------------
// qproj: Qbf[m][j] = bf16(code_l[m] @ W_l^T + b_l). grid 672, block 256.
// ---------------------------------------------------------------------------
__global__ __launch_bounds__(256) void qproj_kern(
    const float* __restrict__ cat_codes, const float* __restrict__ type_codes,
    const float* __restrict__ var_codes, const float* __restrict__ sp_codes,
    const float* __restrict__ cat_w, const float* __restrict__ cat_b,
    const float* __restrict__ type_w, const float* __restrict__ type_b,
    const float* __restrict__ var_w, const float* __restrict__ var_b,
    const float* __restrict__ sp_w, const float* __restrict__ sp_b,
    unsigned short* __restrict__ Qbf) {
  const int m = blockIdx.x;
  const float* code;
  const float* W;
  const float* bias;
  if (m < 16)       { code = cat_codes  + m * 256;         W = cat_w;  bias = cat_b; }
  else if (m < 144) { code = type_codes + (m - 16) * 256;  W = type_w; bias = type_b; }
  else if (m < 656) { code = var_codes  + (m - 144) * 256; W = var_w;  bias = var_b; }
  else              { code = sp_codes   + (m - 656) * 256; W = sp_w;   bias = sp_b; }
  __shared__ float xs[256];
  const int t = threadIdx.x;
  xs[t] = code[t];
  __syncthreads();
  float a = bias[t];
  const float* wr = W + (size_t)t * 256;
  for (int k = 0; k < 256; k += 4) {
    const float4 w = *(const float4*)&wr[k];
    a = fmaf(w.x, xs[k], a);
    a = fmaf(w.y, xs[k + 1], a);
    a = fmaf(w.z, xs[k + 2], a);
    a = fmaf(w.w, xs[k + 3], a);
  }
  Qbf[(size_t)m * 256 + t] = f2bf(a);
}

// ---------------------------------------------------------------------------
// pospool: pos_acc[b][d] += masked sum of positions; cnt[b] += #mask.
// grid (16, 32), block 256. LDS-reduced before atomics.
// ---------------------------------------------------------------------------
__global__ __launch_bounds__(256) void pospool_kern(
    const float* __restrict__ pos, const unsigned char* __restrict__ mask,
    float* __restrict__ pacc, float* __restrict__ cnt) {
  const int b = blockIdx.x, seg = blockIdx.y, t = threadIdx.x;
  const int dg = t & 63;
  const int nl = t >> 6;
  const int n0 = seg * 128;
  float4 acc = make_float4(0.f, 0.f, 0.f, 0.f);
  float c = 0.f;
  const float* pb = pos + (size_t)b * 4096 * 256;
  for (int j = 0; j < 32; ++j) {
    const int n = n0 + j * 4 + nl;
    const unsigned char mk = mask[(size_t)b * 4096 + n];
    if (mk) {
      const float4 v = *(const float4*)&pb[(size_t)n * 256 + dg * 4];
      acc.x += v.x; acc.y += v.y; acc.z += v.z; acc.w += v.w;
      if (dg == 0) c += 1.f;
    }
  }
  __shared__ float4 red4[256];
  __shared__ float redc[4];
  red4[t] = acc;
  if (dg == 0) redc[nl] = c;
  __syncthreads();
  if (t < 64) {
    float4 s = red4[t];
    const float4 s1 = red4[t + 64], s2 = red4[t + 128], s3 = red4[t + 192];
    s.x += s1.x + s2.x + s3.x;
    s.y += s1.y + s2.y + s3.y;
    s.z += s1.z + s2.z + s3.z;
    s.w += s1.w + s2.w + s3.w;
    float* pa = pacc + b * 256 + t * 4;
    atomicAdd(pa + 0, s.x);
    atomicAdd(pa + 1, s.y);
    atomicAdd(pa + 2, s.z);
    atomicAdd(pa + 3, s.w);
    if (t == 0) atomicAdd(&cnt[b], redc[0] + redc[1] + redc[2] + redc[3]);
  }
}

// ---------------------------------------------------------------------------
// combine: wave-parallel softmax/sparsify cascade. All 4 waves duplicate the
// cascade (same-value LDS writes are benign); __syncthreads between stages.
// z-sum skips zero weights via block-uniform LDS broadcast test. grid 16.
// ---------------------------------------------------------------------------
__global__ __launch_bounds__(256) void combine_kern(
    const float* __restrict__ wraw, const float* __restrict__ H,
    float* __restrict__ zbuf) {
  const int b = blockIdx.x, t = threadIdx.x, l = t & 63;
  __shared__ float wr[672];
  __shared__ float wsp[672];
  for (int i = t; i < 672; i += 256) wr[i] = wraw[b * 672 + i];
  __syncthreads();
  // --- category (16, thr 0.1): lane l<16 handles element l ---
  {
    const float v = (l < 16) ? wr[l] : -1e30f;
    const float mx = wave_max(v);
    const float e = (l < 16) ? expf(wr[l] - mx) : 0.f;
    const float s = wave_sum(e);
    float w = e / s;
    w = (w > 0.1f) ? w : 0.f;
    const float s2 = wave_sum(w);
    if (l < 16) wsp[l] = w / (s2 + 1e-8f);
  }
  __syncthreads();
  // --- type (128, thr 0.05): lane l handles elements l and 64+l ---
  {
    const float L0 = wr[16 + l] * wsp[l >> 3];
    const float L1 = wr[16 + 64 + l] * wsp[(64 + l) >> 3];
    const float mx = wave_max(fmaxf(L0, L1));
    const float e0 = expf(L0 - mx), e1 = expf(L1 - mx);
    const float s = wave_sum(e0 + e1);
    float w0 = e0 / s, w1 = e1 / s;
    w0 = (w0 > 0.05f) ? w0 : 0.f;
    w1 = (w1 > 0.05f) ? w1 : 0.f;
    const float s2 = wave_sum(w0 + w1);
    const float inv2 = 1.f / (s2 + 1e-8f);
    wsp[16 + l] = w0 * inv2;
    wsp[16 + 64 + l] = w1 * inv2;
  }
  __syncthreads();
  // --- variant (512, thr 0.025): lane l handles elements l*8..l*8+7 ---
  {
    float Lv[8];
    float lm = -1e30f;
#pragma unroll
    for (int j = 0; j < 8; ++j) {
      const int i = l * 8 + j;
      Lv[j] = wr[144 + i] * wsp[16 + (i >> 2)];
      lm = fmaxf(lm, Lv[j]);
    }
    const float mx = wave_max(lm);
    float ls = 0.f;
#pragma unroll
    for (int j = 0; j < 8; ++j) {
      Lv[j] = expf(Lv[j] - mx);
      ls += Lv[j];
    }
    const float s = wave_sum(ls);
    const float inv = 1.f / s;
    float ls2 = 0.f;
#pragma unroll
    for (int j = 0; j < 8; ++j) {
      float w = Lv[j] * inv;
      w = (w > 0.025f) ? w : 0.f;
      Lv[j] = w;
      ls2 += w;
    }
    const float s2 = wave_sum(ls2);
    const float inv2 = 1.f / (s2 + 1e-8f);
#pragma unroll
    for (int j = 0; j < 8; ++j) wsp[144 + l * 8 + j] = Lv[j] * inv2;
  }
  __syncthreads();
  // --- spatial (16, thr 0.1) ---
  {
    const float v = (l < 16) ? wr[656 + l] : -1e30f;
    const float mx = wave_max(v);
    const float e = (l < 16) ? expf(wr[656 + l] - mx) : 0.f;
    const float s = wave_sum(e);
    float w = e / s;
    w = (w > 0.1f) ? w : 0.f;
    const float s2 = wave_sum(w);
    if (l < 16) wsp[656 + l] = w / (s2 + 1e-8f);
  }
  __syncthreads();
  // --- z-sums with block-uniform zero skip ---
  const float* Hb = H + (size_t)b * 672 * 256 + t;
  float z0 = 0.f, z1 = 0.f, z2 = 0.f, z3 = 0.f;
  for (int m = 0; m < 16; ++m) {
    const float wv = wsp[m];
    if (wv != 0.f) z0 = fmaf(wv, Hb[(size_t)m * 256], z0);
  }
  for (int m = 0; m < 128; ++m) {
    const float wv = wsp[16 + m];
    if (wv != 0.f) z1 = fmaf(wv, Hb[(size_t)(16 + m) * 256], z1);
  }
  for (int m = 0; m < 512; ++m) {
    const float wv = wsp[144 + m];
    if (wv != 0.f) z2 = fmaf(wv, Hb[(size_t)(144 + m) * 256], z2);
  }
  for (int m = 0; m < 16; ++m) {
    const float wv = wsp[656 + m];
    if (wv != 0.f) z3 = fmaf(wv, Hb[(size_t)(656 + m) * 256], z3);
  }
  zbuf[(b * 4 + 0) * 256 + t] = z0;
  zbuf[(b * 4 + 1) * 256 + t] = z1;
  zbuf[(b * 4 + 2) * 256 + t] = z2;
  zbuf[(b * 4 + 3) * 256 + t] = z3;
}

// ---------------------------------------------------------------------------
// gate: pos-gate MLP, level combine, out proj, layernorm. grid 16.
// ---------------------------------------------------------------------------
__global__ __launch_bounds__(256) void gate_kern(
    const float* __restrict__ zbuf, const float* __restrict__ pacc,
    const float* __restrict__ cnt, const float* __restrict__ g1_w,
    const float* __restrict__ g1_b, const float* __restrict__ g2_w,
    const float* __restrict__ g2_b, const float* __restrict__ out_w,
    const float* __restrict__ out_b, const float* __restrict__ ln_g,
    const float* __restrict__ ln_b, const float* __restrict__ lvlw,
    float* __restrict__ out) {
  const int b = blockIdx.x, t = threadIdx.x;
  __shared__ float gin[512];
  __shared__ float hb[256];
  __shared__ float zc[256];
  __shared__ float red[256];
  const float z0 = zbuf[(b * 4 + 0) * 256 + t];
  gin[t] = z0;
  const float c = fmaxf(cnt[b], 1.0f);
  gin[256 + t] = pacc[b * 256 + t] / c;
  __syncthreads();
  float a = g1_b[t];
  const float* w1 = g1_w + (size_t)t * 512;
  for (int k = 0; k < 512; k += 4) {
    const float4 w = *(const float4*)&w1[k];
    a = fmaf(w.x, gin[k], a);
    a = fmaf(w.y, gin[k + 1], a);
    a = fmaf(w.z, gin[k + 2], a);
    a = fmaf(w.w, gin[k + 3], a);
  }
  const float hg = 0.5f * a * (1.0f + erff(a * 0.7071067811865475f));
  hb[t] = hg;
  __syncthreads();
  float a2 = g2_b[t];
  const float* w2 = g2_w + (size_t)t * 256;
  for (int k = 0; k < 256; k += 4) {
    const float4 w = *(const float4*)&w2[k];
    a2 = fmaf(w.x, hb[k], a2);
    a2 = fmaf(w.y, hb[k + 1], a2);
    a2 = fmaf(w.z, hb[k + 2], a2);
    a2 = fmaf(w.w, hb[k + 3], a2);
  }
  const float pg = 1.0f / (1.0f + expf(-a2));
  const float l0 = lvlw[0], l1 = lvlw[1], l2 = lvlw[2], l3 = lvlw[3];
  const float mx = fmaxf(fmaxf(l0, l1), fmaxf(l2, l3));
  const float e0 = expf(l0 - mx), e1 = expf(l1 - mx);
  const float e2 = expf(l2 - mx), e3 = expf(l3 - mx);
  const float einv = 1.0f / (e0 + e1 + e2 + e3);
  const float zmix = (e0 * z0 * pg + e1 * zbuf[(b * 4 + 1) * 256 + t] +
                      e2 * zbuf[(b * 4 + 2) * 256 + t] +
                      e3 * zbuf[(b * 4 + 3) * 256 + t]) * einv;
  zc[t] = zmix;
  __syncthreads();
  float o = out_b[t];
  const float* wo = out_w + (size_t)t * 256;
  for (int k = 0; k < 256; k += 4) {
    const float4 w = *(const float4*)&wo[k];
    o = fmaf(w.x, zc[k], o);
    o = fmaf(w.y, zc[k + 1], o);
    o = fmaf(w.z, zc[k + 2], o);
    o = fmaf(w.w, zc[k + 3], o);
  }
  red[t] = o;
  __syncthreads();
  for (int s = 128; s > 0; s >>= 1) {
    if (t < s) red[t] += red[t + s];
    __syncthreads();
  }
  const float mu = red[0] / 256.f;
  __syncthreads();
  red[t] = o * o;
  __syncthreads();
  for (int s = 128; s > 0; s >>= 1) {
    if (t < s) red[t] += red[t + s];
    __syncthreads();
  }
  const float var = red[0] / 256.f - mu * mu;
  out[b * 256 + t] = (o - mu) * rsqrtf(var + 1e-5f) * ln_g[t] + ln_b[t];
}

// ---------------------------------------------------------------------------
// launch
// ---------------------------------------------------------------------------
extern "C" void kernel_launch(void* const* d_in, const int* in_sizes, int n_in,
                              void* d_out, int out_size, void* d_ws,
                              size_t ws_size, hipStream_t stream) {
  (void)in_sizes; (void)n_in; (void)out_size; (void)ws_size;
  const float* X          = (const float*)d_in[0];
  const float* positions  = (const float*)d_in[1];
  const float* cat_codes  = (const float*)d_in[2];
  const float* type_codes = (const float*)d_in[3];
  const float* var_codes  = (const float*)d_in[4];
  const float* sp_codes   = (const float*)d_in[5];
  const float* log_tau    = (const float*)d_in[6];
  const float* cat_w      = (const float*)d_in[7];
  const float* cat_b      = (const float*)d_in[8];
  const float* type_w     = (const float*)d_in[9];
  const float* type_b     = (const float*)d_in[10];
  const float* var_w      = (const float*)d_in[11];
  const float* var_b      = (const float*)d_in[12];
  const float* sp_w       = (const float*)d_in[13];
  const float* sp_b       = (const float*)d_in[14];
  const float* k_w        = (const float*)d_in[15];
  const float* k_b        = (const float*)d_in[16];
  const float* g1_w       = (const float*)d_in[17];
  const float* g1_b       = (const float*)d_in[18];
  const float* g2_w       = (const float*)d_in[19];
  const float* g2_b       = (const float*)d_in[20];
  const float* out_w      = (const float*)d_in[21];
  const float* out_b      = (const float*)d_in[22];
  const float* ln_g       = (const float*)d_in[23];
  const float* ln_b       = (const float*)d_in[24];
  const float* lvlw       = (const float*)d_in[25];
  const unsigned char* mask = (const unsigned char*)d_in[26];

  char* ws = (char*)d_ws;
  // workspace layout (bytes); Hp aliases Kbf (dead after scores in a chunk)
  constexpr size_t O_KBF = 0;          // bf16 Kbf [8][4096][256] / f32 Hp [2][8][672][256]
  constexpr size_t O_QBF = 16777216;   // bf16 Qbf [672][256]
  constexpr size_t O_S   = 17121280;   // bf16 S [8][672][4096]
  constexpr size_t O_XT  = 61161472;   // bf16 XbfT [8][256][4096]
  constexpr size_t O_H   = 77938688;   // f32 H [16][672][256]
  constexpr size_t O_L   = 88948736;   // f32 lsum [16][672]
  constexpr size_t O_WR  = 88991744;   // f32 wraw [16][672]
  constexpr size_t O_PA  = 89034752;   // f32 pacc [16][256]
  constexpr size_t O_CNT = 89051136;   // f32 cnt [16]
  constexpr size_t O_Z   = 89051200;   // f32 zbuf [16][4][256]

  unsigned short* Kbf = (unsigned short*)(ws + O_KBF);
  float* Hp           = (float*)(ws + O_KBF);
  unsigned short* Qbf = (unsigned short*)(ws + O_QBF);
  unsigned short* S   = (unsigned short*)(ws + O_S);
  unsigned short* XT  = (unsigned short*)(ws + O_XT);
  float* H            = (float*)(ws + O_H);
  float* lsum         = (float*)(ws + O_L);
  float* wraw         = (float*)(ws + O_WR);
  float* pacc         = (float*)(ws + O_PA);
  float* cnt          = (float*)(ws + O_CNT);
  float* zbuf         = (float*)(ws + O_Z);
  float* out          = (float*)d_out;

  hipMemsetAsync(lsum, 0, 16 * 672 * 4, stream);
  hipMemsetAsync(pacc, 0, 16 * 256 * 4, stream);
  hipMemsetAsync(cnt, 0, 64, stream);

  qproj_kern<<<dim3(672), 256, 0, stream>>>(
      cat_codes, type_codes, var_codes, sp_codes, cat_w, cat_b, type_w, type_b,
      var_w, var_b, sp_w, sp_b, Qbf);
  pospool_kern<<<dim3(16, 32), 256, 0, stream>>>(positions, mask, pacc, cnt);

  for (int c = 0; c < 2; ++c) {
    const int bbase = c * 8;
    kproj_mfma<<<dim3(256, 2), 256, 0, stream>>>(X, k_w, k_b, Kbf, bbase);
    xT_kern<<<dim3(64, 4, 8), 256, 0, stream>>>(X, XT, bbase);
    scores_mfma<<<dim3(7, 32, 8), 256, 0, stream>>>(Qbf, Kbf, mask, S, lsum,
                                                    bbase);
    hmat_mfma<<<dim3(7, 2, 16), 256, 0, stream>>>(S, XT, Hp);
    hfinal2<<<dim3(8 * 672), 256, 0, stream>>>(Hp, lsum, log_tau, H, wraw,
                                               bbase);
  }

  combine_kern<<<dim3(16), 256, 0, stream>>>(wraw, H, zbuf);
  gate_kern<<<dim3(16), 256, 0, stream>>>(zbuf, pacc, cnt, g1_w, g1_b, g2_w,
                                          g2_b, out_w, out_b, ln_g, ln_b, lvlw,
                                          out);
}

// Round 4
// 493.925 us; speedup vs baseline: 2.5979x; 1.0499x over previous
//
#include <hip/hip_runtime.h>

// ---------------------------------------------------------------------------
// HierarchicalCodebookGrounding — round 4: flash-fused scores+hmat.
// B=16, N=4096, D=256, codes 672 (cat16|type128|var512|sp16).
// Pipeline (single pass, no batch chunking):
//   qproj      : Qpack  = bf16(codes @ W^T + b)   in MFMA A-frag order
//   kproj_mfma : Kpack  = bf16(X @ k_w^T + k_b)   in MFMA B-frag order
//   xT_kern    : XTpack = bf16(X^T)               in MFMA B-frag order
//   attn_fused : per (m-tile 64, n-slice 2048, b): S=exp(clip(mask(QK^T/16)))
//                in-register, P->LDS (padded), O += P@X, lsum atomics,
//                O -> atomicAdd into H (memset 0). No S materialization.
//   hfinal_ip  : H /= lsum (in place); wraw = ||H||/tau
//   combine    : wave-parallel softmax/sparsify cascade + zero-skip z-sums
//   gate       : MLP + level combine + out proj + LN
// Fragment-order packing: frag[tile][kstep][lane][8] so every MFMA operand
// load is one coalesced 1KB wave load (no LDS staging, no bank conflicts).
// ---------------------------------------------------------------------------

#define DEV static __device__ __forceinline__

typedef short bf16x8 __attribute__((ext_vector_type(8)));
typedef float f32x4 __attribute__((ext_vector_type(4)));
typedef unsigned short u16x8 __attribute__((ext_vector_type(8)));

DEV float bf2f(unsigned short u) {
  return __uint_as_float(((unsigned int)u) << 16);
}
DEV unsigned short f2bf(float f) {
  unsigned int x = __float_as_uint(f);
  unsigned int r = (x + 0x7fffu + ((x >> 16) & 1u)) >> 16;
  return (unsigned short)r;
}

DEV bf16x8 pack8(const float4 a, const float4 b) {
  bf16x8 r;
  r[0] = (short)f2bf(a.x); r[1] = (short)f2bf(a.y);
  r[2] = (short)f2bf(a.z); r[3] = (short)f2bf(a.w);
  r[4] = (short)f2bf(b.x); r[5] = (short)f2bf(b.y);
  r[6] = (short)f2bf(b.z); r[7] = (short)f2bf(b.w);
  return r;
}

// packed fragment address (elements): row-tile rt, k-step ks, slot, j
// layout: [rt][ks(8 per 256k)][64][8]; slot = (row&15) + 16*((k>>3)&3)
DEV size_t pk_off(int rt, int ks) { return ((size_t)rt * 8 + ks) * 512; }

// ---------------------------------------------------------------------------
// kproj_mfma: Kpack = bf16(X @ W^T + bias), rows m = b*4096+n (65536),
// cols c = 256. 128x128 tiles, BK=64, padded LDS (stride 72). grid (512, 2).
// ---------------------------------------------------------------------------
__global__ __launch_bounds__(256) void kproj_mfma(
    const float* __restrict__ X, const float* __restrict__ W,
    const float* __restrict__ bias, unsigned short* __restrict__ Kp) {
  __shared__ __align__(16) unsigned short As[128 * 72];
  __shared__ __align__(16) unsigned short Bs[128 * 72];
  const int m0 = blockIdx.x * 128, c0 = blockIdx.y * 128;
  const int t = threadIdx.x, l = t & 63, w = t >> 6;
  const int wm = (w & 1) * 64, wn = (w >> 1) * 64;
  const f32x4 zero = {0.f, 0.f, 0.f, 0.f};
  f32x4 acc[4][4];
#pragma unroll
  for (int i = 0; i < 4; ++i)
#pragma unroll
    for (int j = 0; j < 4; ++j) acc[i][j] = zero;
  const int rr = t >> 3, cc = (t & 7) * 8;
  for (int kc = 0; kc < 256; kc += 64) {
    __syncthreads();
#pragma unroll
    for (int p = 0; p < 4; ++p) {
      const int r = p * 32 + rr;
      const float* xs = &X[(size_t)(m0 + r) * 256 + kc + cc];
      const float4 a0 = *(const float4*)&xs[0];
      const float4 a1 = *(const float4*)&xs[4];
      *(bf16x8*)&As[r * 72 + cc] = pack8(a0, a1);
      const float* wsrc = &W[(size_t)(c0 + r) * 256 + kc + cc];
      const float4 b0 = *(const float4*)&wsrc[0];
      const float4 b1 = *(const float4*)&wsrc[4];
      *(bf16x8*)&Bs[r * 72 + cc] = pack8(b0, b1);
    }
    __syncthreads();
#pragma unroll
    for (int ks = 0; ks < 2; ++ks) {
      const int koff = ks * 32 + ((l >> 4) & 3) * 8;
      bf16x8 a[4], b[4];
#pragma unroll
      for (int f = 0; f < 4; ++f)
        a[f] = *(const bf16x8*)&As[(wm + f * 16 + (l & 15)) * 72 + koff];
#pragma unroll
      for (int f = 0; f < 4; ++f)
        b[f] = *(const bf16x8*)&Bs[(wn + f * 16 + (l & 15)) * 72 + koff];
#pragma unroll
      for (int i = 0; i < 4; ++i)
#pragma unroll
        for (int j = 0; j < 4; ++j)
          acc[i][j] =
              __builtin_amdgcn_mfma_f32_16x16x32_bf16(a[i], b[j], acc[i][j],
                                                      0, 0, 0);
    }
  }
  const int q = (l >> 4) & 3;
#pragma unroll
  for (int j = 0; j < 4; ++j) {
    const int c = c0 + wn + j * 16 + (l & 15);
    const float bv = bias[c];
#pragma unroll
    for (int i = 0; i < 4; ++i) {
      const int mrow = m0 + wm + i * 16 + q * 4;
#pragma unroll
      for (int r = 0; r < 4; ++r) {
        const int m = mrow + r;
        // packed: [m>>4][c>>5][slot][c&7], slot=(m&15)+16*((c>>3)&3)
        Kp[pk_off(m >> 4, c >> 5) + ((m & 15) + 16 * ((c >> 3) & 3)) * 8 +
           (c & 7)] = f2bf(acc[i][j][r] + bv);
      }
    }
  }
}

// ---------------------------------------------------------------------------
// xT_kern: XTpack[b][d-tiles][n-steps][slot][8] = bf16(X[b][n][d] transposed).
// grid (64, 4, 16).
// ---------------------------------------------------------------------------
__global__ __launch_bounds__(256) void xT_kern(const float* __restrict__ X,
                                               unsigned short* __restrict__ XTp) {
  __shared__ float Ls[64][65];
  const int tn = blockIdx.x, td = blockIdx.y, b = blockIdx.z;
  const int t = threadIdx.x;
  const int nl = t >> 2, dp = (t & 3) * 16;
  const float* src =
      X + ((size_t)b * 4096 + tn * 64 + nl) * 256 + td * 64 + dp;
#pragma unroll
  for (int v = 0; v < 4; ++v) {
    const float4 x = *(const float4*)&src[v * 4];
    Ls[nl][dp + v * 4 + 0] = x.x;
    Ls[nl][dp + v * 4 + 1] = x.y;
    Ls[nl][dp + v * 4 + 2] = x.z;
    Ls[nl][dp + v * 4 + 3] = x.w;
  }
  __syncthreads();
  const int dl = t >> 2, np = (t & 3) * 16;
  u16x8 h0, h1;
#pragma unroll
  for (int j = 0; j < 8; ++j) h0[j] = f2bf(Ls[np + j][dl]);
#pragma unroll
  for (int j = 0; j < 8; ++j) h1[j] = f2bf(Ls[np + 8 + j][dl]);
  const int d = td * 64 + dl;        // 0..255 within batch
  const int n0g = tn * 64 + np;      // multiple of 16
  const int n1g = n0g + 8;
  // per-b packed: [d>>4 (16)][n>>5 (128)][64][8]
  unsigned short* dst = XTp + (size_t)b * 1048576;
  dst[0] = 0;  // no-op guard removed below (kept for clarity none needed)
  const size_t o0 = (((size_t)(d >> 4) * 128) + (n0g >> 5)) * 512 +
                    ((d & 15) + 16 * ((n0g >> 3) & 3)) * 8;
  const size_t o1 = (((size_t)(d >> 4) * 128) + (n1g >> 5)) * 512 +
                    ((d & 15) + 16 * ((n1g >> 3) & 3)) * 8;
  *(u16x8*)&dst[o0] = h0;
  *(u16x8*)&dst[o1] = h1;
}

// ---------------------------------------------------------------------------
// qproj: Qpack[m-tiles 44][8][64][8] = bf16(code @ W^T + b), zero-pad m>=672.
// grid 704, block 256.
// ---------------------------------------------------------------------------
__global__ __launch_bounds__(256) void qproj_kern(
    const float* __restrict__ cat_codes, const float* __restrict__ type_codes,
    const float* __restrict__ var_codes, const float* __restrict__ sp_codes,
    const float* __restrict__ cat_w, const float* __restrict__ cat_b,
    const float* __restrict__ type_w, const float* __restrict__ type_b,
    const float* __restrict__ var_w, const float* __restrict__ var_b,
    const float* __restrict__ sp_w, const float* __restrict__ sp_b,
    unsigned short* __restrict__ Qp) {
  const int m = blockIdx.x;
  const int t = threadIdx.x;
  const size_t off = pk_off(m >> 4, t >> 5) +
                     ((m & 15) + 16 * ((t >> 3) & 3)) * 8 + (t & 7);
  if (m >= 672) {
    Qp[off] = 0;
    return;
  }
  const float* code;
  const float* W;
  const float* bias;
  if (m < 16)       { code = cat_codes  + m * 256;         W = cat_w;  bias = cat_b; }
  else if (m < 144) { code = type_codes + (m - 16) * 256;  W = type_w; bias = type_b; }
  else if (m < 656) { code = var_codes  + (m - 144) * 256; W = var_w;  bias = var_b; }
  else              { code = sp_codes   + (m - 656) * 256; W = sp_w;   bias = sp_b; }
  __shared__ float xs[256];
  xs[t] = code[t];
  __syncthreads();
  float a = bias[t];
  const float* wr = W + (size_t)t * 256;
  for (int k = 0; k < 256; k += 4) {
    const float4 w = *(const float4*)&wr[k];
    a = fmaf(w.x, xs[k], a);
    a = fmaf(w.y, xs[k + 1], a);
    a = fmaf(w.z, xs[k + 2], a);
    a = fmaf(w.w, xs[k + 3], a);
  }
  Qp[off] = f2bf(a);
}

// ---------------------------------------------------------------------------
// attn_fused: per (m-tile 64, n-slice 2048, batch). Q frags persistent in
// regs; K/XT frags loaded direct from packed global (coalesced 1KB/wave);
// P exchanged via padded LDS; O accumulated in regs, atomicAdd into H.
// grid (11, 2, 16), block 256 (4 waves), 2 blocks/CU.
// ---------------------------------------------------------------------------
__global__ __launch_bounds__(256, 2) void attn_fused(
    const unsigned short* __restrict__ Qp, const unsigned short* __restrict__ Kp,
    const unsigned short* __restrict__ XTp,
    const unsigned char* __restrict__ mask, float* __restrict__ H,
    float* __restrict__ lsum) {
  __shared__ __align__(16) unsigned short Plds[64 * 72];
  __shared__ unsigned char msk[2048];
  const int m0 = blockIdx.x * 64;
  const int nbase = blockIdx.y * 2048;
  const int b = blockIdx.z;
  const int t = threadIdx.x, l = t & 63, w = t >> 6;
  const int l15 = l & 15, q = l >> 4;
  ((uint2*)msk)[t] = ((const uint2*)(mask + (size_t)b * 4096 + nbase))[t];
  // persistent Q fragments for this wave's m-tile
  const int mt_g = (m0 >> 4) + w;
  bf16x8 qf[8];
#pragma unroll
  for (int ks = 0; ks < 8; ++ks)
    qf[ks] = *(const bf16x8*)&Qp[pk_off(mt_g, ks) + l * 8];
  const f32x4 zero = {0.f, 0.f, 0.f, 0.f};
  f32x4 accO[4][4];
#pragma unroll
  for (int i = 0; i < 4; ++i)
#pragma unroll
    for (int j = 0; j < 4; ++j) accO[i][j] = zero;
  f32x4 rs = zero;
  __syncthreads();
  for (int c = 0; c < 32; ++c) {
    const int nt0 = (nbase >> 4) + c * 4;  // global n-tile base (16-wide)
    // ---- S phase: S[16 rows of mt_g][64 n] over k=256 ----
    f32x4 accS[4];
#pragma unroll
    for (int f = 0; f < 4; ++f) accS[f] = zero;
#pragma unroll
    for (int ks = 0; ks < 8; ++ks) {
      bf16x8 kf[4];
#pragma unroll
      for (int f = 0; f < 4; ++f)
        kf[f] = *(const bf16x8*)&Kp[pk_off(b * 256 + nt0 + f, ks) + l * 8];
#pragma unroll
      for (int f = 0; f < 4; ++f)
        accS[f] = __builtin_amdgcn_mfma_f32_16x16x32_bf16(qf[ks], kf[f],
                                                          accS[f], 0, 0, 0);
    }
    __syncthreads();  // previous chunk's PV finished reading Plds
    // ---- epilogue: exp + write P (C-layout -> LDS [m][n], stride 72) ----
#pragma unroll
    for (int f = 0; f < 4; ++f) {
      const bool mk = msk[c * 64 + f * 16 + l15] != 0;
#pragma unroll
      for (int r = 0; r < 4; ++r) {
        float s = accS[f][r] * 0.0625f;
        s = fminf(fmaxf(s, -50.f), 50.f);
        if (!mk) s = -50.f;
        const float e = __expf(s);
        Plds[(w * 16 + q * 4 + r) * 72 + f * 16 + l15] = f2bf(e);
        rs[r] += e;
      }
    }
    __syncthreads();
    // ---- PV phase: O[64 m][64 d-strip w] += P[64][64] @ X[64][64] ----
#pragma unroll
    for (int ks2 = 0; ks2 < 2; ++ks2) {
      const int nst = (nbase >> 5) + c * 2 + ks2;
      bf16x8 xf[4], pf[4];
#pragma unroll
      for (int dj = 0; dj < 4; ++dj)
        xf[dj] = *(const bf16x8*)&XTp[(size_t)b * 1048576 +
                                      pk_off((4 * w + dj) * 128 / 8, 0) +
                                      (size_t)nst * 512 + l * 8];
#pragma unroll
      for (int mt = 0; mt < 4; ++mt)
        pf[mt] = *(const bf16x8*)&Plds[(mt * 16 + l15) * 72 + ks2 * 32 + q * 8];
#pragma unroll
      for (int mt = 0; mt < 4; ++mt)
#pragma unroll
        for (int dj = 0; dj < 4; ++dj)
          accO[mt][dj] = __builtin_amdgcn_mfma_f32_16x16x32_bf16(
              pf[mt], xf[dj], accO[mt][dj], 0, 0, 0);
    }
  }
  // ---- lsum: reduce rs over the 16 lanes sharing each row ----
#pragma unroll
  for (int r = 0; r < 4; ++r) {
    float v = rs[r];
    v += __shfl_xor(v, 1, 64);
    v += __shfl_xor(v, 2, 64);
    v += __shfl_xor(v, 4, 64);
    v += __shfl_xor(v, 8, 64);
    const int m = m0 + w * 16 + q * 4 + r;
    if (l15 == 0 && m < 672) atomicAdd(&lsum[b * 672 + m], v);
  }
  // ---- O: atomicAdd into H (n-slices accumulate) ----
#pragma unroll
  for (int mt = 0; mt < 4; ++mt) {
    const int mbase = m0 + mt * 16 + q * 4;
#pragma unroll
    for (int dj = 0; dj < 4; ++dj) {
      const int d = w * 64 + dj * 16 + l15;
#pragma unroll
      for (int r = 0; r < 4; ++r) {
        const int m = mbase + r;
        if (m < 672)
          atomicAdd(&H[((size_t)b * 672 + m) * 256 + d], accO[mt][dj][r]);
      }
    }
  }
}

// ---------------------------------------------------------------------------
// hfinal_ip: H /= lsum in place; wraw = ||H|| / tau. grid 16*672.
// ---------------------------------------------------------------------------
__global__ __launch_bounds__(256) void hfinal_ip(
    float* __restrict__ H, const float* __restrict__ lsum,
    const float* __restrict__ log_tau, float* __restrict__ wraw) {
  const int bm = blockIdx.x;
  const int t = threadIdx.x;
  __shared__ float red[256];
  const float inv = 1.0f / lsum[bm];
  const float v = H[(size_t)bm * 256 + t] * inv;
  H[(size_t)bm * 256 + t] = v;
  red[t] = v * v;
  __syncthreads();
  for (int s = 128; s > 0; s >>= 1) {
    if (t < s) red[t] += red[t + s];
    __syncthreads();
  }
  if (t == 0) {
    const float tau = fminf(fmaxf(expf(log_tau[0]) + 0.1f, 0.1f), 2.0f);
    wraw[bm] = sqrtf(red[0]) / tau;
  }
}

// ---------------------------------------------------------------------------
// pospool: pos_acc[b][d] += masked sum of positions; cnt[b] += #mask.
// grid (16, 32), block 256.
// ---------------------------------------------------------------------------
__global__ __launch_bounds__(256) void pospool_kern(
    const float* __restrict__ pos, const unsigned char* __restrict__ mask,
    float* __restrict__ pacc, float* __restrict__ cnt) {
  const int b = blockIdx.x, seg = blockIdx.y, t = threadIdx.x;
  const int dg = t & 63;
  const int nl = t >> 6;
  const int n0 = seg * 128;
  float4 acc = make_float4(0.f, 0.f, 0.f, 0.f);
  float c = 0.f;
  const float* pb = pos + (size_t)b * 4096 * 256;
  for (int j = 0; j < 32; ++j) {
    const int n = n0 + j * 4 + nl;
    const unsigned char mk = mask[(size_t)b * 4096 + n];
    if (mk) {
      const float4 v = *(const float4*)&pb[(size_t)n * 256 + dg * 4];
      acc.x += v.x; acc.y += v.y; acc.z += v.z; acc.w += v.w;
      if (dg == 0) c += 1.f;
    }
  }
  __shared__ float4 red4[256];
  __shared__ float redc[4];
  red4[t] = acc;
  if (dg == 0) redc[nl] = c;
  __syncthreads();
  if (t < 64) {
    float4 s = red4[t];
    const float4 s1 = red4[t + 64], s2 = red4[t + 128], s3 = red4[t + 192];
    s.x += s1.x + s2.x + s3.x;
    s.y += s1.y + s2.y + s3.y;
    s.z += s1.z + s2.z + s3.z;
    s.w += s1.w + s2.w + s3.w;
    float* pa = pacc + b * 256 + t * 4;
    atomicAdd(pa + 0, s.x);
    atomicAdd(pa + 1, s.y);
    atomicAdd(pa + 2, s.z);
    atomicAdd(pa + 3, s.w);
    if (t == 0) atomicAdd(&cnt[b], redc[0] + redc[1] + redc[2] + redc[3]);
  }
}

DEV float wave_max(float v) {
#pragma unroll
  for (int m = 1; m < 64; m <<= 1) v = fmaxf(v, __shfl_xor(v, m, 64));
  return v;
}
DEV float wave_sum(float v) {
#pragma unroll
  for (int m = 1; m < 64; m <<= 1) v += __shfl_xor(v, m, 64);
  return v;
}

// ---------------------------------------------------------------------------
// combine: wave-parallel softmax/sparsify cascade + zero-skip z-sums. grid 16.
// ---------------------------------------------------------------------------
__global__ __launch_bounds__(256) void combine_kern(
    const float* __restrict__ wraw, const float* __restrict__ H,
    float* __restrict__ zbuf) {
  const int b = blockIdx.x, t = threadIdx.x, l = t & 63;
  __shared__ float wr[672];
  __shared__ float wsp[672];
  for (int i = t; i < 672; i += 256) wr[i] = wraw[b * 672 + i];
  __syncthreads();
  {
    const float v = (l < 16) ? wr[l] : -1e30f;
    const float mx = wave_max(v);
    const float e = (l < 16) ? expf(wr[l] - mx) : 0.f;
    const float s = wave_sum(e);
    float w = e / s;
    w = (w > 0.1f) ? w : 0.f;
    const float s2 = wave_sum(w);
    if (l < 16) wsp[l] = w / (s2 + 1e-8f);
  }
  __syncthreads();
  {
    const float L0 = wr[16 + l] * wsp[l >> 3];
    const float L1 = wr[16 + 64 + l] * wsp[(64 + l) >> 3];
    const float mx = wave_max(fmaxf(L0, L1));
    const float e0 = expf(L0 - mx), e1 = expf(L1 - mx);
    const float s = wave_sum(e0 + e1);
    float w0 = e0 / s, w1 = e1 / s;
    w0 = (w0 > 0.05f) ? w0 : 0.f;
    w1 = (w1 > 0.05f) ? w1 : 0.f;
    const float s2 = wave_sum(w0 + w1);
    const float inv2 = 1.f / (s2 + 1e-8f);
    wsp[16 + l] = w0 * inv2;
    wsp[16 + 64 + l] = w1 * inv2;
  }
  __syncthreads();
  {
    float Lv[8];
    float lm = -1e30f;
#pragma unroll
    for (int j = 0; j < 8; ++j) {
      const int i = l * 8 + j;
      Lv[j] = wr[144 + i] * wsp[16 + (i >> 2)];
      lm = fmaxf(lm, Lv[j]);
    }
    const float mx = wave_max(lm);
    float ls = 0.f;
#pragma unroll
    for (int j = 0; j < 8; ++j) {
      Lv[j] = expf(Lv[j] - mx);
      ls += Lv[j];
    }
    const float s = wave_sum(ls);
    const float inv = 1.f / s;
    float ls2 = 0.f;
#pragma unroll
    for (int j = 0; j < 8; ++j) {
      float w = Lv[j] * inv;
      w = (w > 0.025f) ? w : 0.f;
      Lv[j] = w;
      ls2 += w;
    }
    const float s2 = wave_sum(ls2);
    const float inv2 = 1.f / (s2 + 1e-8f);
#pragma unroll
    for (int j = 0; j < 8; ++j) wsp[144 + l * 8 + j] = Lv[j] * inv2;
  }
  __syncthreads();
  {
    const float v = (l < 16) ? wr[656 + l] : -1e30f;
    const float mx = wave_max(v);
    const float e = (l < 16) ? expf(wr[656 + l] - mx) : 0.f;
    const float s = wave_sum(e);
    float w = e / s;
    w = (w > 0.1f) ? w : 0.f;
    const float s2 = wave_sum(w);
    if (l < 16) wsp[656 + l] = w / (s2 + 1e-8f);
  }
  __syncthreads();
  const float* Hb = H + (size_t)b * 672 * 256 + t;
  float z0 = 0.f, z1 = 0.f, z2 = 0.f, z3 = 0.f;
  for (int m = 0; m < 16; ++m) {
    const float wv = wsp[m];
    if (wv != 0.f) z0 = fmaf(wv, Hb[(size_t)m * 256], z0);
  }
  for (int m = 0; m < 128; ++m) {
    const float wv = wsp[16 + m];
    if (wv != 0.f) z1 = fmaf(wv, Hb[(size_t)(16 + m) * 256], z1);
  }
  for (int m = 0; m < 512; ++m) {
    const float wv = wsp[144 + m];
    if (wv != 0.f) z2 = fmaf(wv, Hb[(size_t)(144 + m) * 256], z2);
  }
  for (int m = 0; m < 16; ++m) {
    const float wv = wsp[656 + m];
    if (wv != 0.f) z3 = fmaf(wv, Hb[(size_t)(656 + m) * 256], z3);
  }
  zbuf[(b * 4 + 0) * 256 + t] = z0;
  zbuf[(b * 4 + 1) * 256 + t] = z1;
  zbuf[(b * 4 + 2) * 256 + t] = z2;
  zbuf[(b * 4 + 3) * 256 + t] = z3;
}

// ---------------------------------------------------------------------------
// gate: pos-gate MLP, level combine, out proj, layernorm. grid 16.
// ---------------------------------------------------------------------------
__global__ __launch_bounds__(256) void gate_kern(
    const float* __restrict__ zbuf, const float* __restrict__ pacc,
    const float* __restrict__ cnt, const float* __restrict__ g1_w,
    const float* __restrict__ g1_b, const float* __restrict__ g2_w,
    const float* __restrict__ g2_b, const float* __restrict__ out_w,
    const float* __restrict__ out_b, const float* __restrict__ ln_g,
    const float* __restrict__ ln_b, const float* __restrict__ lvlw,
    float* __restrict__ out) {
  const int b = blockIdx.x, t = threadIdx.x;
  __shared__ float gin[512];
  __shared__ float hb[256];
  __shared__ float zc[256];
  __shared__ float red[256];
  const float z0 = zbuf[(b * 4 + 0) * 256 + t];
  gin[t] = z0;
  const float c = fmaxf(cnt[b], 1.0f);
  gin[256 + t] = pacc[b * 256 + t] / c;
  __syncthreads();
  float a = g1_b[t];
  const float* w1 = g1_w + (size_t)t * 512;
  for (int k = 0; k < 512; k += 4) {
    const float4 w = *(const float4*)&w1[k];
    a = fmaf(w.x, gin[k], a);
    a = fmaf(w.y, gin[k + 1], a);
    a = fmaf(w.z, gin[k + 2], a);
    a = fmaf(w.w, gin[k + 3], a);
  }
  const float hg = 0.5f * a * (1.0f + erff(a * 0.7071067811865475f));
  hb[t] = hg;
  __syncthreads();
  float a2 = g2_b[t];
  const float* w2 = g2_w + (size_t)t * 256;
  for (int k = 0; k < 256; k += 4) {
    const float4 w = *(const float4*)&w2[k];
    a2 = fmaf(w.x, hb[k], a2);
    a2 = fmaf(w.y, hb[k + 1], a2);
    a2 = fmaf(w.z, hb[k + 2], a2);
    a2 = fmaf(w.w, hb[k + 3], a2);
  }
  const float pg = 1.0f / (1.0f + expf(-a2));
  const float l0 = lvlw[0], l1 = lvlw[1], l2 = lvlw[2], l3 = lvlw[3];
  const float mx = fmaxf(fmaxf(l0, l1), fmaxf(l2, l3));
  const float e0 = expf(l0 - mx), e1 = expf(l1 - mx);
  const float e2 = expf(l2 - mx), e3 = expf(l3 - mx);
  const float einv = 1.0f / (e0 + e1 + e2 + e3);
  const float zmix = (e0 * z0 * pg + e1 * zbuf[(b * 4 + 1) * 256 + t] +
                      e2 * zbuf[(b * 4 + 2) * 256 + t] +
                      e3 * zbuf[(b * 4 + 3) * 256 + t]) * einv;
  zc[t] = zmix;
  __syncthreads();
  float o = out_b[t];
  const float* wo = out_w + (size_t)t * 256;
  for (int k = 0; k < 256; k += 4) {
    const float4 w = *(const float4*)&wo[k];
    o = fmaf(w.x, zc[k], o);
    o = fmaf(w.y, zc[k + 1], o);
    o = fmaf(w.z, zc[k + 2], o);
    o = fmaf(w.w, zc[k + 3], o);
  }
  red[t] = o;
  __syncthreads();
  for (int s = 128; s > 0; s >>= 1) {
    if (t < s) red[t] += red[t + s];
    __syncthreads();
  }
  const float mu = red[0] / 256.f;
  __syncthreads();
  red[t] = o * o;
  __syncthreads();
  for (int s = 128; s > 0; s >>= 1) {
    if (t < s) red[t] += red[t + s];
    __syncthreads();
  }
  const float var = red[0] / 256.f - mu * mu;
  out[b * 256 + t] = (o - mu) * rsqrtf(var + 1e-5f) * ln_g[t] + ln_b[t];
}

// ---------------------------------------------------------------------------
// launch
// ---------------------------------------------------------------------------
extern "C" void kernel_launch(void* const* d_in, const int* in_sizes, int n_in,
                              void* d_out, int out_size, void* d_ws,
                              size_t ws_size, hipStream_t stream) {
  (void)in_sizes; (void)n_in; (void)out_size; (void)ws_size;
  const float* X          = (const float*)d_in[0];
  const float* positions  = (const float*)d_in[1];
  const float* cat_codes  = (const float*)d_in[2];
  const float* type_codes = (const float*)d_in[3];
  const float* var_codes  = (const float*)d_in[4];
  const float* sp_codes   = (const float*)d_in[5];
  const float* log_tau    = (const float*)d_in[6];
  const float* cat_w      = (const float*)d_in[7];
  const float* cat_b      = (const float*)d_in[8];
  const float* type_w     = (const float*)d_in[9];
  const float* type_b     = (const float*)d_in[10];
  const float* var_w      = (const float*)d_in[11];
  const float* var_b      = (const float*)d_in[12];
  const float* sp_w       = (const float*)d_in[13];
  const float* sp_b       = (const float*)d_in[14];
  const float* k_w        = (const float*)d_in[15];
  const float* k_b        = (const float*)d_in[16];
  const float* g1_w       = (const float*)d_in[17];
  const float* g1_b       = (const float*)d_in[18];
  const float* g2_w       = (const float*)d_in[19];
  const float* g2_b       = (const float*)d_in[20];
  const float* out_w      = (const float*)d_in[21];
  const float* out_b      = (const float*)d_in[22];
  const float* ln_g       = (const float*)d_in[23];
  const float* ln_b       = (const float*)d_in[24];
  const float* lvlw       = (const float*)d_in[25];
  const unsigned char* mask = (const unsigned char*)d_in[26];

  char* ws = (char*)d_ws;
  // workspace layout (bytes), total ~78.6 MB
  constexpr size_t O_KP  = 0;          // bf16 Kpack  [16*256][8][64][8] = 33,554,432
  constexpr size_t O_XT  = 33554432;   // bf16 XTpack [16][16][128][512] = 33,554,432
  constexpr size_t O_QP  = 67108864;   // bf16 Qpack  [44][8][64][8]     = 360,448
  constexpr size_t O_H   = 67469312;   // f32 H [16][672][256]           = 11,010,048
  constexpr size_t O_L   = 78479360;   // f32 lsum [16][672]
  constexpr size_t O_WR  = 78522368;   // f32 wraw [16][672]
  constexpr size_t O_PA  = 78565376;   // f32 pacc [16][256]
  constexpr size_t O_CNT = 78581760;   // f32 cnt [16]
  constexpr size_t O_Z   = 78581824;   // f32 zbuf [16][4][256]

  unsigned short* Kp  = (unsigned short*)(ws + O_KP);
  unsigned short* XTp = (unsigned short*)(ws + O_XT);
  unsigned short* Qp  = (unsigned short*)(ws + O_QP);
  float* H            = (float*)(ws + O_H);
  float* lsum         = (float*)(ws + O_L);
  float* wraw         = (float*)(ws + O_WR);
  float* pacc         = (float*)(ws + O_PA);
  float* cnt          = (float*)(ws + O_CNT);
  float* zbuf         = (float*)(ws + O_Z);
  float* out          = (float*)d_out;

  hipMemsetAsync(lsum, 0, 16 * 672 * 4, stream);
  hipMemsetAsync(H, 0, 11010048, stream);
  hipMemsetAsync(pacc, 0, 16 * 256 * 4, stream);
  hipMemsetAsync(cnt, 0, 64, stream);

  qproj_kern<<<dim3(704), 256, 0, stream>>>(
      cat_codes, type_codes, var_codes, sp_codes, cat_w, cat_b, type_w, type_b,
      var_w, var_b, sp_w, sp_b, Qp);
  kproj_mfma<<<dim3(512, 2), 256, 0, stream>>>(X, k_w, k_b, Kp);
  xT_kern<<<dim3(64, 4, 16), 256, 0, stream>>>(X, XTp);
  pospool_kern<<<dim3(16, 32), 256, 0, stream>>>(positions, mask, pacc, cnt);

  attn_fused<<<dim3(11, 2, 16), 256, 0, stream>>>(Qp, Kp, XTp, mask, H, lsum);

  hfinal_ip<<<dim3(16 * 672), 256, 0, stream>>>(H, lsum, log_tau, wraw);
  combine_kern<<<dim3(16), 256, 0, stream>>>(wraw, H, zbuf);
  gate_kern<<<dim3(16), 256, 0, stream>>>(zbuf, pacc, cnt, g1_w, g1_b, g2_w,
                                          g2_b, out_w, out_b, ln_g, ln_b, lvlw,
                                          out);
}